// Round 4
// baseline (464.757 us; speedup 1.0000x reference)
//
#include <hip/hip_runtime.h>
#include <hip/hip_bf16.h>

// SelfAttention_v2: S = x·(Wq^T·Wk)·x^T, causal softmax (post-softmax mask +
// renorm == causal softmax), exact JAX partitionable-threefry dropout p=0.5.
// GEMM: 128x128 tile, 8 waves = 2x2 layout x 2-way intra-block K-split,
// BK=64 double-buffered LDS (2-phase), LDS reduction of the two K-halves.

using bf16   = __bf16;
using bf16x8 = __attribute__((ext_vector_type(8))) __bf16;
using bf16x4 = __attribute__((ext_vector_type(4))) __bf16;
using f32x4  = __attribute__((ext_vector_type(4))) float;

constexpr int Tdim = 4096;
constexpr int Ddim = 1024;

// ---------------- cast f32 -> bf16, x4 vectorized ----------------
__global__ __launch_bounds__(256) void k_cast_bf16(const float* __restrict__ in,
                                                   bf16* __restrict__ out, int n4) {
  int i = blockIdx.x * 256 + threadIdx.x;
  if (i >= n4) return;
  f32x4 v = reinterpret_cast<const f32x4*>(in)[i];
  bf16x4 o;
  o[0] = (bf16)v[0]; o[1] = (bf16)v[1]; o[2] = (bf16)v[2]; o[3] = (bf16)v[3];
  reinterpret_cast<bf16x4*>(out)[i] = o;
}

// ---------------- fused transpose+cast for Wq,Wk ----------------
__global__ __launch_bounds__(256) void k_tcast(const float* __restrict__ q,
                                               const float* __restrict__ k,
                                               bf16* __restrict__ qt,
                                               bf16* __restrict__ kt) {
  const float* in = blockIdx.z ? k : q;
  bf16* out = blockIdx.z ? kt : qt;
  __shared__ float t[32][33];
  const int tx = threadIdx.x & 31;
  const int ty = threadIdx.x >> 5;
  const int r0 = blockIdx.y * 32;
  const int c0 = blockIdx.x * 32;
#pragma unroll
  for (int r = 0; r < 4; ++r)
    t[ty * 4 + r][tx] = in[(r0 + ty * 4 + r) * Ddim + c0 + tx];
  __syncthreads();
#pragma unroll
  for (int r = 0; r < 4; ++r)
    out[(c0 + ty * 4 + r) * Ddim + r0 + tx] = (bf16)t[tx][ty * 4 + r];
}

// ---------------- reduce 4 split-K partials + cast to bf16 ----------------
__global__ __launch_bounds__(256) void k_redcast(const float* __restrict__ p,
                                                 bf16* __restrict__ g) {
  const int i = blockIdx.x * 256 + threadIdx.x;
  f32x4 a = reinterpret_cast<const f32x4*>(p)[i];
  f32x4 b = reinterpret_cast<const f32x4*>(p + (1 << 20))[i];
  f32x4 c = reinterpret_cast<const f32x4*>(p + (2 << 20))[i];
  f32x4 d = reinterpret_cast<const f32x4*>(p + (3 << 20))[i];
  f32x4 s = a + b + c + d;
  bf16x4 o;
  o[0] = (bf16)s[0]; o[1] = (bf16)s[1]; o[2] = (bf16)s[2]; o[3] = (bf16)s[3];
  reinterpret_cast<bf16x4*>(g)[i] = o;
}

__device__ __forceinline__ void gll16(const bf16* g, bf16* l) {
  __builtin_amdgcn_global_load_lds(
      (const __attribute__((address_space(1))) void*)g,
      (__attribute__((address_space(3))) void*)l, 16, 0, 0);
}

// ---------------- bf16 GEMM, C[m,n] = sum_k A[m,k]*B[n,k] ----------------
// 128x128 tile, 8 waves (512 thr): wid = g*4 + w2; g = intra-block K-half,
// w2 = 2x2 wave layout. BK=64/iter double-buffered; group g consumes cols
// [g*32, g*32+32) of each staged tile. LDS reduce merges the halves.
// blockIdx.y = external split-K chunk (k0 = y*kLen, C += y*cZs for f32 out).
template<int OUTF32>
__global__ __launch_bounds__(512)
void k_gemm8(const bf16* __restrict__ A, const bf16* __restrict__ B,
             void* __restrict__ Cv, int N, int lda, int ldb, int kLen,
             long cZs, int causal) {
  union SMem {
    bf16  t[2][2][128 * 64];   // [buf][mat A/B][row*64+col], 64 KB
    float red[256 * 65];       // reduction scratch, padded, 66.6 KB
  };
  __shared__ SMem sm;

  const int nbn = N >> 7;
  int bx = blockIdx.x;
  {  // XCD swizzle (all grids have gridDim.x % 8 == 0)
    const int cpx = gridDim.x >> 3;
    bx = (bx & 7) * cpx + (bx >> 3);
  }
  const int bm = bx / nbn;
  const int bn = bx - bm * nbn;
  if (causal && bn > bm) return;  // fully-masked output block

  const int tid  = threadIdx.x;
  const int lane = tid & 63;
  const int wid  = tid >> 6;         // 0..7
  const int g    = wid >> 2;         // K-half
  const int w2   = wid & 3;
  const int wr   = (w2 >> 1) * 64;
  const int wc   = (w2 & 1) * 64;
  const int fr   = lane & 15;
  const int ko   = g * 32 + (lane >> 4) * 8;  // col within staged 64

  f32x4 acc[4][4];
#pragma unroll
  for (int i = 0; i < 4; ++i)
#pragma unroll
    for (int j = 0; j < 4; ++j) acc[i][j] = (f32x4){0.f, 0.f, 0.f, 0.f};

  const bf16* Ag = A + (long)bm * 128 * lda;
  const bf16* Bg = B + (long)bn * 128 * ldb;
  const int k0 = blockIdx.y * kLen;

  // staging: 1024 16B-chunks per matrix; thread covers chunks tid and tid+512.
  const int r1_ = tid >> 3,          cb1 = (tid & 7) * 8;
  const int r2_ = (tid + 512) >> 3,  cb2 = (tid & 7) * 8;  // (tid+512)&7 == tid&7

  auto stage = [&](int buf, int kt) {
    gll16(Ag + (long)r1_ * lda + kt + cb1, &sm.t[buf][0][tid * 8]);
    gll16(Bg + (long)r1_ * ldb + kt + cb1, &sm.t[buf][1][tid * 8]);
    gll16(Ag + (long)r2_ * lda + kt + cb2, &sm.t[buf][0][(tid + 512) * 8]);
    gll16(Bg + (long)r2_ * ldb + kt + cb2, &sm.t[buf][1][(tid + 512) * 8]);
  };
  auto compute = [&](int buf) {
    bf16x8 av[4], bv[4];
#pragma unroll
    for (int f = 0; f < 4; ++f) {
      av[f] = *reinterpret_cast<const bf16x8*>(&sm.t[buf][0][(wr + f * 16 + fr) * 64 + ko]);
      bv[f] = *reinterpret_cast<const bf16x8*>(&sm.t[buf][1][(wc + f * 16 + fr) * 64 + ko]);
    }
    __builtin_amdgcn_s_setprio(1);
#pragma unroll
    for (int fm = 0; fm < 4; ++fm)
#pragma unroll
      for (int fn = 0; fn < 4; ++fn)
        acc[fm][fn] = __builtin_amdgcn_mfma_f32_16x16x32_bf16(av[fm], bv[fn], acc[fm][fn], 0, 0, 0);
    __builtin_amdgcn_s_setprio(0);
  };

  const int nIter = kLen >> 6;
  stage(0, k0);
  __syncthreads();
  int cur = 0;
  for (int it = 1; it < nIter; ++it) {
    stage(cur ^ 1, k0 + it * 64);  // prefetch next tile into other buffer
    compute(cur);
    __syncthreads();
    cur ^= 1;
  }
  compute(cur);

  // merge the two K-halves: g1 -> LDS (padded stride 65, conflict-free), g0 adds
  __syncthreads();
  const int rrow = w2 * 64 + lane;
  if (g == 1) {
#pragma unroll
    for (int fm = 0; fm < 4; ++fm)
#pragma unroll
      for (int fn = 0; fn < 4; ++fn)
#pragma unroll
        for (int j = 0; j < 4; ++j)
          sm.red[rrow * 65 + fm * 16 + fn * 4 + j] = acc[fm][fn][j];
  }
  __syncthreads();
  if (g == 0) {
    const int crow0 = (lane >> 4) * 4;
    const int ccol  = lane & 15;
#pragma unroll
    for (int fm = 0; fm < 4; ++fm)
#pragma unroll
      for (int fn = 0; fn < 4; ++fn)
#pragma unroll
        for (int j = 0; j < 4; ++j) {
          const float v = acc[fm][fn][j] + sm.red[rrow * 65 + fm * 16 + fn * 4 + j];
          const long row = (long)bm * 128 + wr + fm * 16 + crow0 + j;
          const long col = (long)bn * 128 + wc + fn * 16 + ccol;
          if (OUTF32) ((float*)Cv + (long)blockIdx.y * cZs)[row * N + col] = v;
          else        ((bf16*)Cv)[row * N + col] = (bf16)v;
        }
  }
}

// ---------------- JAX threefry2x32, key = (0,123) ----------------
__device__ __forceinline__ unsigned rotl32(unsigned v, int d) {
  return (v << d) | (v >> (32 - d));
}
__device__ __forceinline__ void threefry_123(unsigned x0, unsigned x1,
                                             unsigned& o0, unsigned& o1) {
  const unsigned ks0 = 0u, ks1 = 123u;
  const unsigned ks2 = 0x1BD11BDAu ^ ks0 ^ ks1;
  x0 += ks0; x1 += ks1;
#define TF_R4(a, b, c, d)                                   \
  x0 += x1; x1 = rotl32(x1, a); x1 ^= x0;                   \
  x0 += x1; x1 = rotl32(x1, b); x1 ^= x0;                   \
  x0 += x1; x1 = rotl32(x1, c); x1 ^= x0;                   \
  x0 += x1; x1 = rotl32(x1, d); x1 ^= x0;
  TF_R4(13, 15, 26, 6);  x0 += ks1; x1 += ks2 + 1u;
  TF_R4(17, 29, 16, 24); x0 += ks2; x1 += ks0 + 2u;
  TF_R4(13, 15, 26, 6);  x0 += ks0; x1 += ks1 + 3u;
  TF_R4(17, 29, 16, 24); x0 += ks1; x1 += ks2 + 4u;
  TF_R4(13, 15, 26, 6);  x0 += ks2; x1 += ks0 + 5u;
#undef TF_R4
  o0 = x0; o1 = x1;
}
// partitionable scheme: bits = o0^o1, counter (0, i); keep = top bit clear
__device__ __forceinline__ bool keep_bit(unsigned i) {
  unsigned o0, o1;
  threefry_123(0u, i, o0, o1);
  return ((o0 ^ o1) & 0x80000000u) == 0u;
}

// ---------------- fused in-place causal softmax + dropout ----------------
// Block b: rows r0=b (cols<2048, threads 0..127) and r1=b+2048 (all threads).
// Thread t owns 16 consecutive cols [16t,16t+16), f32x4 loads/stores.
__global__ __launch_bounds__(256) void k_softmax_drop(float* __restrict__ S) {
  const int b  = blockIdx.x;
  const int r0 = b, r1 = b + (Tdim / 2);
  const int tid = threadIdx.x;
  const int cb  = tid * 16;
  __shared__ float redA[4], redB[4];

  float* row0 = S + (long)r0 * Tdim;
  float* row1 = S + (long)r1 * Tdim;

  f32x4 v1[4], v0[4];
  float lm0 = -3.0e38f, lm1 = -3.0e38f;
#pragma unroll
  for (int i = 0; i < 4; ++i) {
    const int c = cb + i * 4;
    f32x4 v = (c <= r1) ? *reinterpret_cast<const f32x4*>(row1 + c)
                        : (f32x4){0.f, 0.f, 0.f, 0.f};
#pragma unroll
    for (int l = 0; l < 4; ++l) {
      if (c + l > r1) v[l] = -3.0e38f;
      lm1 = fmaxf(lm1, v[l]);
    }
    v1[i] = v;
  }
  if (tid < 128) {
#pragma unroll
    for (int i = 0; i < 4; ++i) {
      const int c = cb + i * 4;
      f32x4 v = (c <= r0) ? *reinterpret_cast<const f32x4*>(row0 + c)
                          : (f32x4){0.f, 0.f, 0.f, 0.f};
#pragma unroll
      for (int l = 0; l < 4; ++l) {
        if (c + l > r0) v[l] = -3.0e38f;
        lm0 = fmaxf(lm0, v[l]);
      }
      v0[i] = v;
    }
  }
#pragma unroll
  for (int o = 32; o; o >>= 1) {
    lm0 = fmaxf(lm0, __shfl_xor(lm0, o));
    lm1 = fmaxf(lm1, __shfl_xor(lm1, o));
  }
  if ((tid & 63) == 0) { redA[tid >> 6] = lm0; redB[tid >> 6] = lm1; }
  __syncthreads();
  const float m0 = fmaxf(fmaxf(redA[0], redA[1]), fmaxf(redA[2], redA[3]));
  const float m1 = fmaxf(fmaxf(redB[0], redB[1]), fmaxf(redB[2], redB[3]));
  __syncthreads();

  constexpr float SC = 1.0f / 32.0f;  // 1/sqrt(1024)
  float ls0 = 0.f, ls1 = 0.f;
#pragma unroll
  for (int i = 0; i < 4; ++i) {
#pragma unroll
    for (int l = 0; l < 4; ++l) {
      const int c = cb + i * 4 + l;
      float e = 0.f;
      if (c <= r1) { e = __expf((v1[i][l] - m1) * SC); ls1 += e; }
      v1[i][l] = e;
    }
  }
  if (tid < 128) {
#pragma unroll
    for (int i = 0; i < 4; ++i) {
#pragma unroll
      for (int l = 0; l < 4; ++l) {
        const int c = cb + i * 4 + l;
        float e = 0.f;
        if (c <= r0) { e = __expf((v0[i][l] - m0) * SC); ls0 += e; }
        v0[i][l] = e;
      }
    }
  }
#pragma unroll
  for (int o = 32; o; o >>= 1) { ls0 += __shfl_xor(ls0, o); ls1 += __shfl_xor(ls1, o); }
  if ((tid & 63) == 0) { redA[tid >> 6] = ls0; redB[tid >> 6] = ls1; }
  __syncthreads();
  const float inv0 = 2.0f / (redA[0] + redA[1] + redA[2] + redA[3]);
  const float inv1 = 2.0f / (redB[0] + redB[1] + redB[2] + redB[3]);

#pragma unroll
  for (int i = 0; i < 4; ++i) {
    const int c = cb + i * 4;
    f32x4 o1v = {0.f, 0.f, 0.f, 0.f};
#pragma unroll
    for (int l = 0; l < 4; ++l) {
      const int cc = c + l;
      if (cc <= r1 && keep_bit((unsigned)(r1 * Tdim + cc))) o1v[l] = v1[i][l] * inv1;
    }
    *reinterpret_cast<f32x4*>(row1 + c) = o1v;
    f32x4 o0v = {0.f, 0.f, 0.f, 0.f};
    if (tid < 128) {
#pragma unroll
      for (int l = 0; l < 4; ++l) {
        const int cc = c + l;
        if (cc <= r0 && keep_bit((unsigned)(r0 * Tdim + cc))) o0v[l] = v0[i][l] * inv0;
      }
    }
    *reinterpret_cast<f32x4*>(row0 + c) = o0v;
  }
}

extern "C" void kernel_launch(void* const* d_in, const int* in_sizes, int n_in,
                              void* d_out, int out_size, void* d_ws, size_t ws_size,
                              hipStream_t stream) {
  const float* x  = (const float*)d_in[0];
  const float* Wq = (const float*)d_in[1];
  const float* Wk = (const float*)d_in[2];
  // d_in[3] (W_value) feeds only dead code in the reference — unused.
  float* S = (float*)d_out;
  char* ws = (char*)d_ws;
  bf16*  xb = (bf16*)(ws);                  //  8 MB: x bf16
  bf16*  qt = (bf16*)(ws + (8l  << 20));    //  2 MB: Wq^T bf16
  bf16*  kt = (bf16*)(ws + (10l << 20));    //  2 MB: Wk^T bf16
  float* Wp = (float*)(ws + (12l << 20));   // 16 MB: 4 split-K partials of G
  bf16*  G  = (bf16*)(ws + (28l << 20));    //  2 MB: G = Wk^T·Wq
  bf16*  P  = (bf16*)(ws + (30l << 20));    //  8 MB: P = x·(Wq^T·Wk)

  k_cast_bf16<<<(Tdim * Ddim / 4) / 256, 256, 0, stream>>>(x, xb, Tdim * Ddim / 4);
  k_tcast<<<dim3(32, 32, 2), 256, 0, stream>>>(Wq, Wk, qt, kt);

  // G partials: G[i,j] = sum_k Wk[k,i]*Wq[k,j], external split-K=4
  k_gemm8<1><<<dim3(64, 4), 512, 0, stream>>>(kt, qt, (void*)Wp, Ddim, Ddim, Ddim,
                                              Ddim / 4, 1l << 20, 0);
  k_redcast<<<(Ddim * Ddim / 4) / 256, 256, 0, stream>>>(Wp, G);

  // P[m,n] = sum_k x[m,k]*G[n,k]
  k_gemm8<0><<<dim3(256, 1), 512, 0, stream>>>(xb, G, (void*)P, Ddim, Ddim, Ddim,
                                               Ddim, 0, 0);
  // S[m,n] = sum_k P[m,k]*x[n,k], causal blocks only
  k_gemm8<1><<<dim3(1024, 1), 512, 0, stream>>>(P, xb, (void*)S, Tdim, Ddim, Ddim,
                                                Ddim, 0, 1);

  k_softmax_drop<<<Tdim / 2, 256, 0, stream>>>(S);
}

// Round 5
// 246.449 us; speedup vs baseline: 1.8858x; 1.8858x over previous
//
#include <hip/hip_runtime.h>
#include <hip/hip_bf16.h>

// SelfAttention_v2: S = x·(Wq^T·Wk)·x^T, causal softmax (post-softmax mask +
// renorm == causal softmax), exact JAX partitionable-threefry dropout p=0.5.
// GEMM: 128x128 tile, 8 waves (2x2 layout x 2-way intra-block K-split),
// BK=64 double-buffered LDS, T2 XOR-swizzle (pre-swizzled global source +
// swizzled ds_read; LDS dest linear — global_load_lds rule #21).

using bf16   = __bf16;
using bf16x8 = __attribute__((ext_vector_type(8))) __bf16;
using bf16x4 = __attribute__((ext_vector_type(4))) __bf16;
using f32x4  = __attribute__((ext_vector_type(4))) float;

constexpr int Tdim = 4096;
constexpr int Ddim = 1024;

// ---------------- cast f32 -> bf16, x4 vectorized ----------------
__global__ __launch_bounds__(256) void k_cast_bf16(const float* __restrict__ in,
                                                   bf16* __restrict__ out, int n4) {
  int i = blockIdx.x * 256 + threadIdx.x;
  if (i >= n4) return;
  f32x4 v = reinterpret_cast<const f32x4*>(in)[i];
  bf16x4 o;
  o[0] = (bf16)v[0]; o[1] = (bf16)v[1]; o[2] = (bf16)v[2]; o[3] = (bf16)v[3];
  reinterpret_cast<bf16x4*>(out)[i] = o;
}

// ---------------- fused transpose+cast for Wq,Wk ----------------
__global__ __launch_bounds__(256) void k_tcast(const float* __restrict__ q,
                                               const float* __restrict__ k,
                                               bf16* __restrict__ qt,
                                               bf16* __restrict__ kt) {
  const float* in = blockIdx.z ? k : q;
  bf16* out = blockIdx.z ? kt : qt;
  __shared__ float t[32][33];
  const int tx = threadIdx.x & 31;
  const int ty = threadIdx.x >> 5;
  const int r0 = blockIdx.y * 32;
  const int c0 = blockIdx.x * 32;
#pragma unroll
  for (int r = 0; r < 4; ++r)
    t[ty * 4 + r][tx] = in[(r0 + ty * 4 + r) * Ddim + c0 + tx];
  __syncthreads();
#pragma unroll
  for (int r = 0; r < 4; ++r)
    out[(c0 + ty * 4 + r) * Ddim + r0 + tx] = (bf16)t[tx][ty * 4 + r];
}

// ---------------- reduce 4 split-K partials + cast to bf16 ----------------
__global__ __launch_bounds__(256) void k_redcast(const float* __restrict__ p,
                                                 bf16* __restrict__ g) {
  const int i = blockIdx.x * 256 + threadIdx.x;
  f32x4 a = reinterpret_cast<const f32x4*>(p)[i];
  f32x4 b = reinterpret_cast<const f32x4*>(p + (1 << 20))[i];
  f32x4 c = reinterpret_cast<const f32x4*>(p + (2 << 20))[i];
  f32x4 d = reinterpret_cast<const f32x4*>(p + (3 << 20))[i];
  f32x4 s = a + b + c + d;
  bf16x4 o;
  o[0] = (bf16)s[0]; o[1] = (bf16)s[1]; o[2] = (bf16)s[2]; o[3] = (bf16)s[3];
  reinterpret_cast<bf16x4*>(g)[i] = o;
}

__device__ __forceinline__ void gll16(const bf16* g, bf16* l) {
  __builtin_amdgcn_global_load_lds(
      (const __attribute__((address_space(1))) void*)g,
      (__attribute__((address_space(3))) void*)l, 16, 0, 0);
}

// ---------------- bf16 GEMM, C[m,n] = sum_k A[m,k]*B[n,k] ----------------
// 128x128 tile, 8 waves (512 thr): wid = g*4 + w2; g = intra-block K-half,
// w2 = 2x2 wave layout. BK=64/iter double-buffered; group g consumes chunks
// [g*4, g*4+4) (8 elems each) of each staged tile row.
// LDS tile row = 8 chunks of 16B; chunk at position p holds logical chunk
// p ^ (row&7)  (involution; applied on global src AND on ds_read addr).
template<int OUTF32>
__global__ __launch_bounds__(512)
void k_gemm8(const bf16* __restrict__ A, const bf16* __restrict__ B,
             void* __restrict__ Cv, int N, int lda, int ldb, int kLen,
             long cZs, int causal) {
  union SMem {
    bf16  t[2][2][128 * 64];   // [buf][mat A/B][row*64+col], 64 KB
    float red[256 * 65];       // reduction scratch, padded
  };
  __shared__ SMem sm;

  const int nbn = N >> 7;
  int bx = blockIdx.x;
  {  // XCD swizzle (all grids have gridDim.x % 8 == 0)
    const int cpx = gridDim.x >> 3;
    bx = (bx & 7) * cpx + (bx >> 3);
  }
  const int bm = bx / nbn;
  const int bn = bx - bm * nbn;
  if (causal && bn > bm) return;  // fully-masked output block

  const int tid  = threadIdx.x;
  const int lane = tid & 63;
  const int wid  = tid >> 6;         // 0..7
  const int g    = wid >> 2;         // K-half
  const int w2   = wid & 3;
  const int wr   = (w2 >> 1) * 64;
  const int wc   = (w2 & 1) * 64;
  const int fr   = lane & 15;
  const int jko  = g * 4 + (lane >> 4);  // logical 16B-chunk index (0..7)

  f32x4 acc[4][4];
#pragma unroll
  for (int i = 0; i < 4; ++i)
#pragma unroll
    for (int j = 0; j < 4; ++j) acc[i][j] = (f32x4){0.f, 0.f, 0.f, 0.f};

  const bf16* Ag = A + (long)bm * 128 * lda;
  const bf16* Bg = B + (long)bn * 128 * ldb;
  const int k0 = blockIdx.y * kLen;

  // staging: 1024 16B-chunks per matrix; thread covers chunks tid and tid+512.
  // LDS dest linear (chunk c at byte c*16); global src chunk = pos ^ (row&7).
  const int rA = tid >> 3;
  const int rB = (tid + 512) >> 3;
  const int jA = ((tid & 7) ^ (rA & 7)) * 8;  // src elem offset within row
  const int jB = ((tid & 7) ^ (rB & 7)) * 8;

  auto stage = [&](int buf, int kt) {
    gll16(Ag + (long)rA * lda + kt + jA, &sm.t[buf][0][tid * 8]);
    gll16(Bg + (long)rA * ldb + kt + jA, &sm.t[buf][1][tid * 8]);
    gll16(Ag + (long)rB * lda + kt + jB, &sm.t[buf][0][(tid + 512) * 8]);
    gll16(Bg + (long)rB * ldb + kt + jB, &sm.t[buf][1][(tid + 512) * 8]);
  };
  auto compute = [&](int buf) {
    bf16x8 av[4], bv[4];
#pragma unroll
    for (int f = 0; f < 4; ++f) {
      const int ra = wr + f * 16 + fr;
      const int rb = wc + f * 16 + fr;
      av[f] = *reinterpret_cast<const bf16x8*>(
          &sm.t[buf][0][ra * 64 + ((jko ^ (ra & 7)) * 8)]);
      bv[f] = *reinterpret_cast<const bf16x8*>(
          &sm.t[buf][1][rb * 64 + ((jko ^ (rb & 7)) * 8)]);
    }
    __builtin_amdgcn_s_setprio(1);
#pragma unroll
    for (int fm = 0; fm < 4; ++fm)
#pragma unroll
      for (int fn = 0; fn < 4; ++fn)
        acc[fm][fn] = __builtin_amdgcn_mfma_f32_16x16x32_bf16(av[fm], bv[fn], acc[fm][fn], 0, 0, 0);
    __builtin_amdgcn_s_setprio(0);
  };

  const int nIter = kLen >> 6;
  stage(0, k0);
  __syncthreads();
  int cur = 0;
  for (int it = 1; it < nIter; ++it) {
    stage(cur ^ 1, k0 + it * 64);  // prefetch next tile into other buffer
    compute(cur);
    __syncthreads();
    cur ^= 1;
  }
  compute(cur);

  // merge the two K-halves: g1 -> LDS (padded stride 65), g0 adds + stores
  __syncthreads();
  const int rrow = w2 * 64 + lane;
  if (g == 1) {
#pragma unroll
    for (int fm = 0; fm < 4; ++fm)
#pragma unroll
      for (int fn = 0; fn < 4; ++fn)
#pragma unroll
        for (int j = 0; j < 4; ++j)
          sm.red[rrow * 65 + fm * 16 + fn * 4 + j] = acc[fm][fn][j];
  }
  __syncthreads();
  if (g == 0) {
    const int crow0 = (lane >> 4) * 4;
    const int ccol  = lane & 15;
#pragma unroll
    for (int fm = 0; fm < 4; ++fm)
#pragma unroll
      for (int fn = 0; fn < 4; ++fn)
#pragma unroll
        for (int j = 0; j < 4; ++j) {
          const float v = acc[fm][fn][j] + sm.red[rrow * 65 + fm * 16 + fn * 4 + j];
          const long row = (long)bm * 128 + wr + fm * 16 + crow0 + j;
          const long col = (long)bn * 128 + wc + fn * 16 + ccol;
          if (OUTF32) ((float*)Cv + (long)blockIdx.y * cZs)[row * N + col] = v;
          else        ((bf16*)Cv)[row * N + col] = (bf16)v;
        }
  }
}

// ---------------- JAX threefry2x32, key = (0,123) ----------------
__device__ __forceinline__ unsigned rotl32(unsigned v, int d) {
  return (v << d) | (v >> (32 - d));
}
__device__ __forceinline__ void threefry_123(unsigned x0, unsigned x1,
                                             unsigned& o0, unsigned& o1) {
  const unsigned ks0 = 0u, ks1 = 123u;
  const unsigned ks2 = 0x1BD11BDAu ^ ks0 ^ ks1;
  x0 += ks0; x1 += ks1;
#define TF_R4(a, b, c, d)                                   \
  x0 += x1; x1 = rotl32(x1, a); x1 ^= x0;                   \
  x0 += x1; x1 = rotl32(x1, b); x1 ^= x0;                   \
  x0 += x1; x1 = rotl32(x1, c); x1 ^= x0;                   \
  x0 += x1; x1 = rotl32(x1, d); x1 ^= x0;
  TF_R4(13, 15, 26, 6);  x0 += ks1; x1 += ks2 + 1u;
  TF_R4(17, 29, 16, 24); x0 += ks2; x1 += ks0 + 2u;
  TF_R4(13, 15, 26, 6);  x0 += ks0; x1 += ks1 + 3u;
  TF_R4(17, 29, 16, 24); x0 += ks1; x1 += ks2 + 4u;
  TF_R4(13, 15, 26, 6);  x0 += ks2; x1 += ks0 + 5u;
#undef TF_R4
  o0 = x0; o1 = x1;
}
// partitionable scheme: bits = o0^o1, counter (0, i); keep = top bit clear
__device__ __forceinline__ bool keep_bit(unsigned i) {
  unsigned o0, o1;
  threefry_123(0u, i, o0, o1);
  return ((o0 ^ o1) & 0x80000000u) == 0u;
}

// ---------------- fused in-place causal softmax + dropout ----------------
// Block b: rows r0=b (cols<2048, threads 0..127) and r1=b+2048 (all threads).
// Thread t owns 16 consecutive cols [16t,16t+16), f32x4 loads/stores.
__global__ __launch_bounds__(256) void k_softmax_drop(float* __restrict__ S) {
  const int b  = blockIdx.x;
  const int r0 = b, r1 = b + (Tdim / 2);
  const int tid = threadIdx.x;
  const int cb  = tid * 16;
  __shared__ float redA[4], redB[4];

  float* row0 = S + (long)r0 * Tdim;
  float* row1 = S + (long)r1 * Tdim;

  f32x4 v1[4], v0[4];
  float lm0 = -3.0e38f, lm1 = -3.0e38f;
#pragma unroll
  for (int i = 0; i < 4; ++i) {
    const int c = cb + i * 4;
    f32x4 v = (c <= r1) ? *reinterpret_cast<const f32x4*>(row1 + c)
                        : (f32x4){0.f, 0.f, 0.f, 0.f};
#pragma unroll
    for (int l = 0; l < 4; ++l) {
      if (c + l > r1) v[l] = -3.0e38f;
      lm1 = fmaxf(lm1, v[l]);
    }
    v1[i] = v;
  }
  if (tid < 128) {
#pragma unroll
    for (int i = 0; i < 4; ++i) {
      const int c = cb + i * 4;
      f32x4 v = (c <= r0) ? *reinterpret_cast<const f32x4*>(row0 + c)
                          : (f32x4){0.f, 0.f, 0.f, 0.f};
#pragma unroll
      for (int l = 0; l < 4; ++l) {
        if (c + l > r0) v[l] = -3.0e38f;
        lm0 = fmaxf(lm0, v[l]);
      }
      v0[i] = v;
    }
  }
#pragma unroll
  for (int o = 32; o; o >>= 1) {
    lm0 = fmaxf(lm0, __shfl_xor(lm0, o));
    lm1 = fmaxf(lm1, __shfl_xor(lm1, o));
  }
  if ((tid & 63) == 0) { redA[tid >> 6] = lm0; redB[tid >> 6] = lm1; }
  __syncthreads();
  const float m0 = fmaxf(fmaxf(redA[0], redA[1]), fmaxf(redA[2], redA[3]));
  const float m1 = fmaxf(fmaxf(redB[0], redB[1]), fmaxf(redB[2], redB[3]));
  __syncthreads();

  constexpr float SC = 1.0f / 32.0f;  // 1/sqrt(1024)
  float ls0 = 0.f, ls1 = 0.f;
#pragma unroll
  for (int i = 0; i < 4; ++i) {
#pragma unroll
    for (int l = 0; l < 4; ++l) {
      const int c = cb + i * 4 + l;
      float e = 0.f;
      if (c <= r1) { e = __expf((v1[i][l] - m1) * SC); ls1 += e; }
      v1[i][l] = e;
    }
  }
  if (tid < 128) {
#pragma unroll
    for (int i = 0; i < 4; ++i) {
#pragma unroll
      for (int l = 0; l < 4; ++l) {
        const int c = cb + i * 4 + l;
        float e = 0.f;
        if (c <= r0) { e = __expf((v0[i][l] - m0) * SC); ls0 += e; }
        v0[i][l] = e;
      }
    }
  }
#pragma unroll
  for (int o = 32; o; o >>= 1) { ls0 += __shfl_xor(ls0, o); ls1 += __shfl_xor(ls1, o); }
  if ((tid & 63) == 0) { redA[tid >> 6] = ls0; redB[tid >> 6] = ls1; }
  __syncthreads();
  const float inv0 = 2.0f / (redA[0] + redA[1] + redA[2] + redA[3]);
  const float inv1 = 2.0f / (redB[0] + redB[1] + redB[2] + redB[3]);

#pragma unroll
  for (int i = 0; i < 4; ++i) {
    const int c = cb + i * 4;
    f32x4 o1v = {0.f, 0.f, 0.f, 0.f};
#pragma unroll
    for (int l = 0; l < 4; ++l) {
      const int cc = c + l;
      if (cc <= r1 && keep_bit((unsigned)(r1 * Tdim + cc))) o1v[l] = v1[i][l] * inv1;
    }
    *reinterpret_cast<f32x4*>(row1 + c) = o1v;
    f32x4 o0v = {0.f, 0.f, 0.f, 0.f};
    if (tid < 128) {
#pragma unroll
      for (int l = 0; l < 4; ++l) {
        const int cc = c + l;
        if (cc <= r0 && keep_bit((unsigned)(r0 * Tdim + cc))) o0v[l] = v0[i][l] * inv0;
      }
    }
    *reinterpret_cast<f32x4*>(row0 + c) = o0v;
  }
}

extern "C" void kernel_launch(void* const* d_in, const int* in_sizes, int n_in,
                              void* d_out, int out_size, void* d_ws, size_t ws_size,
                              hipStream_t stream) {
  const float* x  = (const float*)d_in[0];
  const float* Wq = (const float*)d_in[1];
  const float* Wk = (const float*)d_in[2];
  // d_in[3] (W_value) feeds only dead code in the reference — unused.
  float* S = (float*)d_out;
  char* ws = (char*)d_ws;
  bf16*  xb = (bf16*)(ws);                  //  8 MB: x bf16
  bf16*  qt = (bf16*)(ws + (8l  << 20));    //  2 MB: Wq^T bf16
  bf16*  kt = (bf16*)(ws + (10l << 20));    //  2 MB: Wk^T bf16
  float* Wp = (float*)(ws + (12l << 20));   // 16 MB: 4 split-K partials of G
  bf16*  G  = (bf16*)(ws + (28l << 20));    //  2 MB: G = Wk^T·Wq
  bf16*  P  = (bf16*)(ws + (30l << 20));    //  8 MB: P = x·(Wq^T·Wk)

  k_cast_bf16<<<(Tdim * Ddim / 4) / 256, 256, 0, stream>>>(x, xb, Tdim * Ddim / 4);
  k_tcast<<<dim3(32, 32, 2), 256, 0, stream>>>(Wq, Wk, qt, kt);

  // G partials: G[i,j] = sum_k Wk[k,i]*Wq[k,j], external split-K=4
  k_gemm8<1><<<dim3(64, 4), 512, 0, stream>>>(kt, qt, (void*)Wp, Ddim, Ddim, Ddim,
                                              Ddim / 4, 1l << 20, 0);
  k_redcast<<<(Ddim * Ddim / 4) / 256, 256, 0, stream>>>(Wp, G);

  // P[m,n] = sum_k x[m,k]*G[n,k]
  k_gemm8<0><<<dim3(256, 1), 512, 0, stream>>>(xb, G, (void*)P, Ddim, Ddim, Ddim,
                                               Ddim, 0, 0);
  // S[m,n] = sum_k P[m,k]*x[n,k], causal blocks only
  k_gemm8<1><<<dim3(1024, 1), 512, 0, stream>>>(P, xb, (void*)S, Tdim, Ddim, Ddim,
                                                Ddim, 0, 1);

  k_softmax_drop<<<Tdim / 2, 256, 0, stream>>>(S);
}

// Round 6
// 200.993 us; speedup vs baseline: 2.3123x; 1.2262x over previous
//
#include <hip/hip_runtime.h>
#include <hip/hip_bf16.h>

// SelfAttention_v2: S = x·(Wq^T·Wk)·x^T, causal softmax (post-softmax mask +
// renorm == causal softmax), exact JAX partitionable-threefry dropout p=0.5.
// GEMM: round-3 proven 128xBN tile, BK=32, 4 waves, PLUS T4 counted-vmcnt
// pipeline: 3 LDS buffers, depth-2 prefetch, raw s_barrier, vmcnt never 0
// in the main loop.

using bf16   = __bf16;
using bf16x8 = __attribute__((ext_vector_type(8))) __bf16;
using bf16x4 = __attribute__((ext_vector_type(4))) __bf16;
using f32x4  = __attribute__((ext_vector_type(4))) float;

constexpr int Tdim = 4096;
constexpr int Ddim = 1024;

// ---------------- cast f32 -> bf16, x4 vectorized ----------------
__global__ __launch_bounds__(256) void k_cast_bf16(const float* __restrict__ in,
                                                   bf16* __restrict__ out, int n4) {
  int i = blockIdx.x * 256 + threadIdx.x;
  if (i >= n4) return;
  f32x4 v = reinterpret_cast<const f32x4*>(in)[i];
  bf16x4 o;
  o[0] = (bf16)v[0]; o[1] = (bf16)v[1]; o[2] = (bf16)v[2]; o[3] = (bf16)v[3];
  reinterpret_cast<bf16x4*>(out)[i] = o;
}

// ---------------- fused transpose+cast for Wq,Wk ----------------
__global__ __launch_bounds__(256) void k_tcast(const float* __restrict__ q,
                                               const float* __restrict__ k,
                                               bf16* __restrict__ qt,
                                               bf16* __restrict__ kt) {
  const float* in = blockIdx.z ? k : q;
  bf16* out = blockIdx.z ? kt : qt;
  __shared__ float t[32][33];
  const int tx = threadIdx.x & 31;
  const int ty = threadIdx.x >> 5;
  const int r0 = blockIdx.y * 32;
  const int c0 = blockIdx.x * 32;
#pragma unroll
  for (int r = 0; r < 4; ++r)
    t[ty * 4 + r][tx] = in[(r0 + ty * 4 + r) * Ddim + c0 + tx];
  __syncthreads();
#pragma unroll
  for (int r = 0; r < 4; ++r)
    out[(c0 + ty * 4 + r) * Ddim + r0 + tx] = (bf16)t[tx][ty * 4 + r];
}

// ---------------- reduce 4 split-K partials + cast to bf16 ----------------
__global__ __launch_bounds__(256) void k_redcast(const float* __restrict__ p,
                                                 bf16* __restrict__ g) {
  const int i = blockIdx.x * 256 + threadIdx.x;
  f32x4 a = reinterpret_cast<const f32x4*>(p)[i];
  f32x4 b = reinterpret_cast<const f32x4*>(p + (1 << 20))[i];
  f32x4 c = reinterpret_cast<const f32x4*>(p + (2 << 20))[i];
  f32x4 d = reinterpret_cast<const f32x4*>(p + (3 << 20))[i];
  f32x4 s = a + b + c + d;
  bf16x4 o;
  o[0] = (bf16)s[0]; o[1] = (bf16)s[1]; o[2] = (bf16)s[2]; o[3] = (bf16)s[3];
  reinterpret_cast<bf16x4*>(g)[i] = o;
}

__device__ __forceinline__ void gll16(const bf16* g, bf16* l) {
  __builtin_amdgcn_global_load_lds(
      (const __attribute__((address_space(1))) void*)g,
      (__attribute__((address_space(3))) void*)l, 16, 0, 0);
}

// ---------------- bf16 GEMM, C[m,n] = sum_k A[m,k]*B[n,k] ----------------
// 128 x BN tile, BK=32, 4 waves (2x2). T4 counted-vmcnt pipeline:
// 3 LDS buffers, depth-2 prefetch. Per iter t:
//   s_waitcnt vmcnt(LPT)   // tile t landed; tile t+1's LPT loads in flight
//   s_barrier              // cross-wave: whole tile t visible
//   stage(t+2)             // into buf[(t+2)%3] == buf[(t-1)%3] (freed by bar)
//   compute(t)
// Last iter drains vmcnt(0). blockIdx.y = external split-K chunk.
template<int OUTF32, int BN>
__global__ __launch_bounds__(256)
void k_gemm_bt(const bf16* __restrict__ A, const bf16* __restrict__ B,
               void* __restrict__ Cv, int N, int lda, int ldb, int kLen,
               long cZs, int causal) {
  constexpr int LPT = 2 + BN / 64;  // gll16 per thread per stage: 4 (BN=128) / 3
  __shared__ __align__(16) bf16 As[3][128 * 32];
  __shared__ __align__(16) bf16 Bs[3][BN * 32];

  const int nbn = N / BN;
  const int bm = blockIdx.x / nbn;
  const int bn = blockIdx.x - bm * nbn;
  if (causal && bn * BN >= bm * 128 + 128) return;  // fully-masked block

  const int tid  = threadIdx.x;
  const int lane = tid & 63;
  const int wid  = tid >> 6;
  const int wr   = (wid >> 1) * 64;
  constexpr int WCW = BN / 2;   // wave col width
  constexpr int FN  = WCW / 16; // 4 (BN=128) or 2 (BN=64)
  const int wc   = (wid & 1) * WCW;
  const int fr   = lane & 15;
  const int ko   = (lane >> 4) * 8;

  f32x4 acc[4][FN];
#pragma unroll
  for (int i = 0; i < 4; ++i)
#pragma unroll
    for (int j = 0; j < FN; ++j) acc[i][j] = (f32x4){0.f, 0.f, 0.f, 0.f};

  const bf16* Ag = A + (long)bm * 128 * lda;
  const bf16* Bg = B + (long)bn * BN * ldb;
  const int k0 = blockIdx.y * kLen;
  const int sr = tid >> 2;          // staging row (0..63)
  const int sc = (tid & 3) * 8;     // staging col elems

  auto stage = [&](int buf, int kt) {
    gll16(Ag + (long)sr * lda + kt + sc,        &As[buf][tid * 8]);
    gll16(Ag + (long)(sr + 64) * lda + kt + sc, &As[buf][(tid + 256) * 8]);
    gll16(Bg + (long)sr * ldb + kt + sc,        &Bs[buf][tid * 8]);
    if constexpr (BN == 128)
      gll16(Bg + (long)(sr + 64) * ldb + kt + sc, &Bs[buf][(tid + 256) * 8]);
  };
  auto compute = [&](int buf) {
    bf16x8 av[4], bv[FN];
#pragma unroll
    for (int f = 0; f < 4; ++f)
      av[f] = *reinterpret_cast<const bf16x8*>(&As[buf][(wr + f * 16 + fr) * 32 + ko]);
#pragma unroll
    for (int f = 0; f < FN; ++f)
      bv[f] = *reinterpret_cast<const bf16x8*>(&Bs[buf][(wc + f * 16 + fr) * 32 + ko]);
    __builtin_amdgcn_s_setprio(1);
#pragma unroll
    for (int fm = 0; fm < 4; ++fm)
#pragma unroll
      for (int fn = 0; fn < FN; ++fn)
        acc[fm][fn] = __builtin_amdgcn_mfma_f32_16x16x32_bf16(av[fm], bv[fn], acc[fm][fn], 0, 0, 0);
    __builtin_amdgcn_s_setprio(0);
  };

  const int nIter = kLen >> 5;
  stage(0, k0);
  stage(1, k0 + 32);
  int cur = 0;
  for (int t = 0; t < nIter - 1; ++t) {
    if constexpr (LPT == 4) asm volatile("s_waitcnt vmcnt(4)" ::: "memory");
    else                    asm volatile("s_waitcnt vmcnt(3)" ::: "memory");
    __builtin_amdgcn_sched_barrier(0);
    __builtin_amdgcn_s_barrier();
    __builtin_amdgcn_sched_barrier(0);
    asm volatile("" ::: "memory");
    if (t + 2 < nIter) stage(cur >= 1 ? cur - 1 : cur + 2, k0 + (t + 2) * 32);
    compute(cur);
    cur = (cur == 2) ? 0 : cur + 1;
  }
  asm volatile("s_waitcnt vmcnt(0)" ::: "memory");
  __builtin_amdgcn_sched_barrier(0);
  __builtin_amdgcn_s_barrier();
  __builtin_amdgcn_sched_barrier(0);
  asm volatile("" ::: "memory");
  compute(cur);

  // epilogue: C/D layout col=lane&15, row=(lane>>4)*4+reg (m89/m91-verified)
  const int crow0 = (lane >> 4) * 4;
  const int ccol  = lane & 15;
#pragma unroll
  for (int fm = 0; fm < 4; ++fm)
#pragma unroll
    for (int fn = 0; fn < FN; ++fn)
#pragma unroll
      for (int j = 0; j < 4; ++j) {
        const long row = (long)bm * 128 + wr + fm * 16 + crow0 + j;
        const long col = (long)bn * BN + wc + fn * 16 + ccol;
        const float v = acc[fm][fn][j];
        if (OUTF32) ((float*)Cv + (long)blockIdx.y * cZs)[row * N + col] = v;
        else        ((bf16*)Cv)[row * N + col] = (bf16)v;
      }
}

// ---------------- JAX threefry2x32, key = (0,123) ----------------
__device__ __forceinline__ unsigned rotl32(unsigned v, int d) {
  return (v << d) | (v >> (32 - d));
}
__device__ __forceinline__ void threefry_123(unsigned x0, unsigned x1,
                                             unsigned& o0, unsigned& o1) {
  const unsigned ks0 = 0u, ks1 = 123u;
  const unsigned ks2 = 0x1BD11BDAu ^ ks0 ^ ks1;
  x0 += ks0; x1 += ks1;
#define TF_R4(a, b, c, d)                                   \
  x0 += x1; x1 = rotl32(x1, a); x1 ^= x0;                   \
  x0 += x1; x1 = rotl32(x1, b); x1 ^= x0;                   \
  x0 += x1; x1 = rotl32(x1, c); x1 ^= x0;                   \
  x0 += x1; x1 = rotl32(x1, d); x1 ^= x0;
  TF_R4(13, 15, 26, 6);  x0 += ks1; x1 += ks2 + 1u;
  TF_R4(17, 29, 16, 24); x0 += ks2; x1 += ks0 + 2u;
  TF_R4(13, 15, 26, 6);  x0 += ks0; x1 += ks1 + 3u;
  TF_R4(17, 29, 16, 24); x0 += ks1; x1 += ks2 + 4u;
  TF_R4(13, 15, 26, 6);  x0 += ks2; x1 += ks0 + 5u;
#undef TF_R4
  o0 = x0; o1 = x1;
}
// partitionable scheme: bits = o0^o1, counter (0, i); keep = top bit clear
__device__ __forceinline__ bool keep_bit(unsigned i) {
  unsigned o0, o1;
  threefry_123(0u, i, o0, o1);
  return ((o0 ^ o1) & 0x80000000u) == 0u;
}

// ---------------- fused in-place causal softmax + dropout ----------------
// Block b: rows r0=b (cols<2048, threads 0..127) and r1=b+2048 (all threads).
// Thread t owns 16 consecutive cols [16t,16t+16), f32x4 loads/stores.
__global__ __launch_bounds__(256) void k_softmax_drop(float* __restrict__ S) {
  const int b  = blockIdx.x;
  const int r0 = b, r1 = b + (Tdim / 2);
  const int tid = threadIdx.x;
  const int cb  = tid * 16;
  __shared__ float redA[4], redB[4];

  float* row0 = S + (long)r0 * Tdim;
  float* row1 = S + (long)r1 * Tdim;

  f32x4 v1[4], v0[4];
  float lm0 = -3.0e38f, lm1 = -3.0e38f;
#pragma unroll
  for (int i = 0; i < 4; ++i) {
    const int c = cb + i * 4;
    f32x4 v = (c <= r1) ? *reinterpret_cast<const f32x4*>(row1 + c)
                        : (f32x4){0.f, 0.f, 0.f, 0.f};
#pragma unroll
    for (int l = 0; l < 4; ++l) {
      if (c + l > r1) v[l] = -3.0e38f;
      lm1 = fmaxf(lm1, v[l]);
    }
    v1[i] = v;
  }
  if (tid < 128) {
#pragma unroll
    for (int i = 0; i < 4; ++i) {
      const int c = cb + i * 4;
      f32x4 v = (c <= r0) ? *reinterpret_cast<const f32x4*>(row0 + c)
                          : (f32x4){0.f, 0.f, 0.f, 0.f};
#pragma unroll
      for (int l = 0; l < 4; ++l) {
        if (c + l > r0) v[l] = -3.0e38f;
        lm0 = fmaxf(lm0, v[l]);
      }
      v0[i] = v;
    }
  }
#pragma unroll
  for (int o = 32; o; o >>= 1) {
    lm0 = fmaxf(lm0, __shfl_xor(lm0, o));
    lm1 = fmaxf(lm1, __shfl_xor(lm1, o));
  }
  if ((tid & 63) == 0) { redA[tid >> 6] = lm0; redB[tid >> 6] = lm1; }
  __syncthreads();
  const float m0 = fmaxf(fmaxf(redA[0], redA[1]), fmaxf(redA[2], redA[3]));
  const float m1 = fmaxf(fmaxf(redB[0], redB[1]), fmaxf(redB[2], redB[3]));
  __syncthreads();

  constexpr float SC = 1.0f / 32.0f;  // 1/sqrt(1024)
  float ls0 = 0.f, ls1 = 0.f;
#pragma unroll
  for (int i = 0; i < 4; ++i) {
#pragma unroll
    for (int l = 0; l < 4; ++l) {
      const int c = cb + i * 4 + l;
      float e = 0.f;
      if (c <= r1) { e = __expf((v1[i][l] - m1) * SC); ls1 += e; }
      v1[i][l] = e;
    }
  }
  if (tid < 128) {
#pragma unroll
    for (int i = 0; i < 4; ++i) {
#pragma unroll
      for (int l = 0; l < 4; ++l) {
        const int c = cb + i * 4 + l;
        float e = 0.f;
        if (c <= r0) { e = __expf((v0[i][l] - m0) * SC); ls0 += e; }
        v0[i][l] = e;
      }
    }
  }
#pragma unroll
  for (int o = 32; o; o >>= 1) { ls0 += __shfl_xor(ls0, o); ls1 += __shfl_xor(ls1, o); }
  if ((tid & 63) == 0) { redA[tid >> 6] = ls0; redB[tid >> 6] = ls1; }
  __syncthreads();
  const float inv0 = 2.0f / (redA[0] + redA[1] + redA[2] + redA[3]);
  const float inv1 = 2.0f / (redB[0] + redB[1] + redB[2] + redB[3]);

#pragma unroll
  for (int i = 0; i < 4; ++i) {
    const int c = cb + i * 4;
    f32x4 o1v = {0.f, 0.f, 0.f, 0.f};
#pragma unroll
    for (int l = 0; l < 4; ++l) {
      const int cc = c + l;
      if (cc <= r1 && keep_bit((unsigned)(r1 * Tdim + cc))) o1v[l] = v1[i][l] * inv1;
    }
    *reinterpret_cast<f32x4*>(row1 + c) = o1v;
    f32x4 o0v = {0.f, 0.f, 0.f, 0.f};
    if (tid < 128) {
#pragma unroll
      for (int l = 0; l < 4; ++l) {
        const int cc = c + l;
        if (cc <= r0 && keep_bit((unsigned)(r0 * Tdim + cc))) o0v[l] = v0[i][l] * inv0;
      }
    }
    *reinterpret_cast<f32x4*>(row0 + c) = o0v;
  }
}

extern "C" void kernel_launch(void* const* d_in, const int* in_sizes, int n_in,
                              void* d_out, int out_size, void* d_ws, size_t ws_size,
                              hipStream_t stream) {
  const float* x  = (const float*)d_in[0];
  const float* Wq = (const float*)d_in[1];
  const float* Wk = (const float*)d_in[2];
  // d_in[3] (W_value) feeds only dead code in the reference — unused.
  float* S = (float*)d_out;
  char* ws = (char*)d_ws;
  bf16*  xb = (bf16*)(ws);                  //  8 MB: x bf16
  bf16*  qt = (bf16*)(ws + (8l  << 20));    //  2 MB: Wq^T bf16
  bf16*  kt = (bf16*)(ws + (10l << 20));    //  2 MB: Wk^T bf16
  float* Wp = (float*)(ws + (12l << 20));   // 16 MB: 4 split-K partials of G
  bf16*  G  = (bf16*)(ws + (28l << 20));    //  2 MB: G = Wk^T·Wq
  bf16*  P  = (bf16*)(ws + (30l << 20));    //  8 MB: P = x·(Wq^T·Wk)

  k_cast_bf16<<<(Tdim * Ddim / 4) / 256, 256, 0, stream>>>(x, xb, Tdim * Ddim / 4);
  k_tcast<<<dim3(32, 32, 2), 256, 0, stream>>>(Wq, Wk, qt, kt);

  // G partials: G[i,j] = sum_k Wk[k,i]*Wq[k,j], external split-K=4
  k_gemm_bt<1, 128><<<dim3(64, 4), 256, 0, stream>>>(kt, qt, (void*)Wp, Ddim, Ddim,
                                                     Ddim, Ddim / 4, 1l << 20, 0);
  k_redcast<<<(Ddim * Ddim / 4) / 256, 256, 0, stream>>>(Wp, G);

  // P[m,n] = sum_k x[m,k]*G[n,k]  (BN=64 -> 512 blocks, 2/CU)
  k_gemm_bt<0, 64><<<dim3(512, 1), 256, 0, stream>>>(xb, G, (void*)P, Ddim, Ddim,
                                                     Ddim, Ddim, 0, 0);
  // S[m,n] = sum_k P[m,k]*x[n,k], causal blocks only
  k_gemm_bt<1, 128><<<dim3(1024, 1), 256, 0, stream>>>(P, xb, (void*)S, Tdim, Ddim,
                                                       Ddim, Ddim, 0, 1);

  k_softmax_drop<<<Tdim / 2, 256, 0, stream>>>(S);
}

// Round 7
// 194.986 us; speedup vs baseline: 2.3835x; 1.0308x over previous
//
#include <hip/hip_runtime.h>
#include <hip/hip_bf16.h>

// SelfAttention_v2: S = x·(Wq^T·Wk)·x^T, causal softmax (post-softmax mask +
// renorm == causal softmax), exact JAX partitionable-threefry dropout p=0.5.
// GEMM: 256x256 (S) / 128x256 (P,G) tile, BK=32, 8 waves (2Mx4N), QUAD-buffered
// LDS with counted-vmcnt deep pipeline: stage tile t+3 during tile t, wait
// vmcnt(2*LPT) at tile top (never 0 in steady state), one s_barrier per tile.

using bf16   = __bf16;
using bf16x8 = __attribute__((ext_vector_type(8))) __bf16;
using bf16x4 = __attribute__((ext_vector_type(4))) __bf16;
using f32x4  = __attribute__((ext_vector_type(4))) float;

constexpr int Tdim = 4096;
constexpr int Ddim = 1024;

// ---------------- cast f32 -> bf16, x4 vectorized ----------------
__global__ __launch_bounds__(256) void k_cast_bf16(const float* __restrict__ in,
                                                   bf16* __restrict__ out, int n4) {
  int i = blockIdx.x * 256 + threadIdx.x;
  if (i >= n4) return;
  f32x4 v = reinterpret_cast<const f32x4*>(in)[i];
  bf16x4 o;
  o[0] = (bf16)v[0]; o[1] = (bf16)v[1]; o[2] = (bf16)v[2]; o[3] = (bf16)v[3];
  reinterpret_cast<bf16x4*>(out)[i] = o;
}

// ---------------- fused transpose+cast for Wq,Wk ----------------
__global__ __launch_bounds__(256) void k_tcast(const float* __restrict__ q,
                                               const float* __restrict__ k,
                                               bf16* __restrict__ qt,
                                               bf16* __restrict__ kt) {
  const float* in = blockIdx.z ? k : q;
  bf16* out = blockIdx.z ? kt : qt;
  __shared__ float t[32][33];
  const int tx = threadIdx.x & 31;
  const int ty = threadIdx.x >> 5;
  const int r0 = blockIdx.y * 32;
  const int c0 = blockIdx.x * 32;
#pragma unroll
  for (int r = 0; r < 4; ++r)
    t[ty * 4 + r][tx] = in[(r0 + ty * 4 + r) * Ddim + c0 + tx];
  __syncthreads();
#pragma unroll
  for (int r = 0; r < 4; ++r)
    out[(c0 + ty * 4 + r) * Ddim + r0 + tx] = (bf16)t[tx][ty * 4 + r];
}

// ---------------- reduce 4 split-K partials + cast to bf16 ----------------
__global__ __launch_bounds__(256) void k_redcast(const float* __restrict__ p,
                                                 bf16* __restrict__ g) {
  const int i = blockIdx.x * 256 + threadIdx.x;
  f32x4 a = reinterpret_cast<const f32x4*>(p)[i];
  f32x4 b = reinterpret_cast<const f32x4*>(p + (1 << 20))[i];
  f32x4 c = reinterpret_cast<const f32x4*>(p + (2 << 20))[i];
  f32x4 d = reinterpret_cast<const f32x4*>(p + (3 << 20))[i];
  f32x4 s = a + b + c + d;
  bf16x4 o;
  o[0] = (bf16)s[0]; o[1] = (bf16)s[1]; o[2] = (bf16)s[2]; o[3] = (bf16)s[3];
  reinterpret_cast<bf16x4*>(g)[i] = o;
}

__device__ __forceinline__ void gll16(const bf16* g, bf16* l) {
  __builtin_amdgcn_global_load_lds(
      (const __attribute__((address_space(1))) void*)g,
      (__attribute__((address_space(3))) void*)l, 16, 0, 0);
}

// ---------------- bf16 GEMM, C[m,n] = sum_k A[m,k]*B[n,k] ----------------
// BM x 256 tile, BK=32, 8 waves = 2M x 4N (wave out: BM/2 rows x 64 cols).
// Quad-buffered LDS; during tile t the block stages tile t+3 (LPT gll/thread);
// at tile top: s_waitcnt vmcnt(2*LPT) [tail: LPT, 0] + one s_barrier.
// Safety: stage(t+3) targets buf (t+3)%4, disjoint from bufs t..t+2; writes to
// buf t%4 (= stage(t)) are proven landed by the vmcnt+barrier at tile-top t;
// next overwrite (stage(t+4)) issues only after barrier t+1, when all waves'
// reads of buf t%4 are complete. BK=32 row-stride 64B: ds_read_b128 pattern is
// bank-optimal (8 accesses per bank over the 8 minimum cycles) — no swizzle.
template<int BM, int OUTF32>
__global__ __launch_bounds__(512)
void k_gemm(const bf16* __restrict__ A, const bf16* __restrict__ B,
            void* __restrict__ Cv, int N, int lda, int ldb, int kLen,
            long cZs, int causal) {
  constexpr int LPT = (BM == 256) ? 4 : 3;  // gll per thread per K-tile
  constexpr int FM  = BM / 32;              // m-frags per wave
  __shared__ __align__(16) bf16 As[4][BM * 32];
  __shared__ __align__(16) bf16 Bs[4][256 * 32];

  int bx = blockIdx.x;
  {  // XCD swizzle (all grids %8 == 0)
    const int cpx = gridDim.x >> 3;
    bx = (bx & 7) * cpx + (bx >> 3);
  }
  const int nbn = N >> 8;
  const int bm = bx / nbn;
  const int bn = bx - bm * nbn;
  if (causal && bn > bm) return;  // fully-masked 256x256 block (BM==256 path)

  const int tid  = threadIdx.x;
  const int lane = tid & 63;
  const int wid  = tid >> 6;            // 0..7
  const int wrr  = (wid >> 2) * (BM / 2);
  const int wcc  = (wid & 3) * 64;
  const int fr   = lane & 15;
  const int g8   = (lane >> 4) * 8;     // k-elem offset within 32

  f32x4 acc[FM][4];
#pragma unroll
  for (int i = 0; i < FM; ++i)
#pragma unroll
    for (int j = 0; j < 4; ++j) acc[i][j] = (f32x4){0.f, 0.f, 0.f, 0.f};

  const bf16* Ag = A + (long)bm * BM * lda;
  const bf16* Bg = B + (long)bn * 256 * ldb;
  const int k0 = blockIdx.y * kLen;
  const int nt = kLen >> 5;

  // staging: 16B chunk c -> row c>>2, elems (c&3)*8; LDS linear at c*16B.
  const bf16* pa0 = Ag + (long)(tid >> 2) * lda + (tid & 3) * 8;
  const bf16* pa1 = pa0 + (long)128 * lda;  // BM==256 only
  const bf16* pb0 = Bg + (long)(tid >> 2) * ldb + (tid & 3) * 8;
  const bf16* pb1 = pb0 + (long)128 * ldb;

  auto stageA = [&](int buf, int kt) {
    gll16(pa0 + kt, &As[buf][tid * 8]);
    if constexpr (BM == 256) gll16(pa1 + kt, &As[buf][(tid + 512) * 8]);
  };
  auto stageB = [&](int buf, int kt) {
    gll16(pb0 + kt, &Bs[buf][tid * 8]);
    gll16(pb1 + kt, &Bs[buf][(tid + 512) * 8]);
  };

  // prologue: tiles 0,1,2 (oldest-first for vmcnt counting)
  stageA(0, k0);      stageB(0, k0);
  stageA(1, k0 + 32); stageB(1, k0 + 32);
  stageA(2, k0 + 64); stageB(2, k0 + 64);

  for (int t = 0; t < nt; ++t) {
    const int buf = t & 3;
    // tile t must be landed; tiles t+1,t+2 (if staged) may remain in flight
    if (t < nt - 2) {
      if constexpr (BM == 256) asm volatile("s_waitcnt vmcnt(8)" ::: "memory");
      else                     asm volatile("s_waitcnt vmcnt(6)" ::: "memory");
    } else if (t == nt - 2) {
      if constexpr (BM == 256) asm volatile("s_waitcnt vmcnt(4)" ::: "memory");
      else                     asm volatile("s_waitcnt vmcnt(3)" ::: "memory");
    } else {
      asm volatile("s_waitcnt vmcnt(0)" ::: "memory");
    }
    __builtin_amdgcn_sched_barrier(0);
    __builtin_amdgcn_s_barrier();
    __builtin_amdgcn_sched_barrier(0);

    const int ks = k0 + (t + 3) * 32;
    const bool more = (t + 3) < nt;
    const int nbuf = (t + 3) & 3;

    bf16x8 av[4], bv[4];
#pragma unroll
    for (int n = 0; n < 4; ++n)
      bv[n] = *reinterpret_cast<const bf16x8*>(&Bs[buf][(wcc + n * 16 + fr) * 32 + g8]);
#pragma unroll
    for (int m = 0; m < 4; ++m)
      av[m] = *reinterpret_cast<const bf16x8*>(&As[buf][(wrr + m * 16 + fr) * 32 + g8]);
    if (more) stageA(nbuf, ks);
    __builtin_amdgcn_s_setprio(1);
#pragma unroll
    for (int m = 0; m < 4; ++m)
#pragma unroll
      for (int n = 0; n < 4; ++n)
        acc[m][n] = __builtin_amdgcn_mfma_f32_16x16x32_bf16(av[m], bv[n], acc[m][n], 0, 0, 0);
    __builtin_amdgcn_s_setprio(0);

    if constexpr (BM == 256) {
#pragma unroll
      for (int m = 0; m < 4; ++m)
        av[m] = *reinterpret_cast<const bf16x8*>(&As[buf][(wrr + (m + 4) * 16 + fr) * 32 + g8]);
      if (more) stageB(nbuf, ks);
      __builtin_amdgcn_s_setprio(1);
#pragma unroll
      for (int m = 0; m < 4; ++m)
#pragma unroll
        for (int n = 0; n < 4; ++n)
          acc[m + 4][n] = __builtin_amdgcn_mfma_f32_16x16x32_bf16(av[m], bv[n], acc[m + 4][n], 0, 0, 0);
      __builtin_amdgcn_s_setprio(0);
    } else {
      if (more) stageB(nbuf, ks);
    }
  }

  // epilogue: C/D layout col=lane&15, row=(lane>>4)*4+reg (m89/m91-verified)
  const int crow = (lane >> 4) * 4;
  const int ccol = lane & 15;
#pragma unroll
  for (int m = 0; m < FM; ++m)
#pragma unroll
    for (int n = 0; n < 4; ++n)
#pragma unroll
      for (int j = 0; j < 4; ++j) {
        const long row = (long)bm * BM + wrr + m * 16 + crow + j;
        const long col = (long)bn * 256 + wcc + n * 16 + ccol;
        const float v = acc[m][n][j];
        if (OUTF32) ((float*)Cv + (long)blockIdx.y * cZs)[row * N + col] = v;
        else        ((bf16*)Cv)[row * N + col] = (bf16)v;
      }
}

// ---------------- JAX threefry2x32, key = (0,123) ----------------
__device__ __forceinline__ unsigned rotl32(unsigned v, int d) {
  return (v << d) | (v >> (32 - d));
}
__device__ __forceinline__ void threefry_123(unsigned x0, unsigned x1,
                                             unsigned& o0, unsigned& o1) {
  const unsigned ks0 = 0u, ks1 = 123u;
  const unsigned ks2 = 0x1BD11BDAu ^ ks0 ^ ks1;
  x0 += ks0; x1 += ks1;
#define TF_R4(a, b, c, d)                                   \
  x0 += x1; x1 = rotl32(x1, a); x1 ^= x0;                   \
  x0 += x1; x1 = rotl32(x1, b); x1 ^= x0;                   \
  x0 += x1; x1 = rotl32(x1, c); x1 ^= x0;                   \
  x0 += x1; x1 = rotl32(x1, d); x1 ^= x0;
  TF_R4(13, 15, 26, 6);  x0 += ks1; x1 += ks2 + 1u;
  TF_R4(17, 29, 16, 24); x0 += ks2; x1 += ks0 + 2u;
  TF_R4(13, 15, 26, 6);  x0 += ks0; x1 += ks1 + 3u;
  TF_R4(17, 29, 16, 24); x0 += ks1; x1 += ks2 + 4u;
  TF_R4(13, 15, 26, 6);  x0 += ks2; x1 += ks0 + 5u;
#undef TF_R4
  o0 = x0; o1 = x1;
}
// partitionable scheme: bits = o0^o1, counter (0, i); keep = top bit clear
__device__ __forceinline__ bool keep_bit(unsigned i) {
  unsigned o0, o1;
  threefry_123(0u, i, o0, o1);
  return ((o0 ^ o1) & 0x80000000u) == 0u;
}

// ---------------- fused in-place causal softmax + dropout ----------------
// Block b: rows r0=b (cols<2048, threads 0..127) and r1=b+2048 (all threads).
// Thread t owns 16 consecutive cols [16t,16t+16), f32x4 loads/stores.
__global__ __launch_bounds__(256) void k_softmax_drop(float* __restrict__ S) {
  const int b  = blockIdx.x;
  const int r0 = b, r1 = b + (Tdim / 2);
  const int tid = threadIdx.x;
  const int cb  = tid * 16;
  __shared__ float redA[4], redB[4];

  float* row0 = S + (long)r0 * Tdim;
  float* row1 = S + (long)r1 * Tdim;

  f32x4 v1[4], v0[4];
  float lm0 = -3.0e38f, lm1 = -3.0e38f;
#pragma unroll
  for (int i = 0; i < 4; ++i) {
    const int c = cb + i * 4;
    f32x4 v = (c <= r1) ? *reinterpret_cast<const f32x4*>(row1 + c)
                        : (f32x4){0.f, 0.f, 0.f, 0.f};
#pragma unroll
    for (int l = 0; l < 4; ++l) {
      if (c + l > r1) v[l] = -3.0e38f;
      lm1 = fmaxf(lm1, v[l]);
    }
    v1[i] = v;
  }
  if (tid < 128) {
#pragma unroll
    for (int i = 0; i < 4; ++i) {
      const int c = cb + i * 4;
      f32x4 v = (c <= r0) ? *reinterpret_cast<const f32x4*>(row0 + c)
                          : (f32x4){0.f, 0.f, 0.f, 0.f};
#pragma unroll
      for (int l = 0; l < 4; ++l) {
        if (c + l > r0) v[l] = -3.0e38f;
        lm0 = fmaxf(lm0, v[l]);
      }
      v0[i] = v;
    }
  }
#pragma unroll
  for (int o = 32; o; o >>= 1) {
    lm0 = fmaxf(lm0, __shfl_xor(lm0, o));
    lm1 = fmaxf(lm1, __shfl_xor(lm1, o));
  }
  if ((tid & 63) == 0) { redA[tid >> 6] = lm0; redB[tid >> 6] = lm1; }
  __syncthreads();
  const float m0 = fmaxf(fmaxf(redA[0], redA[1]), fmaxf(redA[2], redA[3]));
  const float m1 = fmaxf(fmaxf(redB[0], redB[1]), fmaxf(redB[2], redB[3]));
  __syncthreads();

  constexpr float SC = 1.0f / 32.0f;  // 1/sqrt(1024)
  float ls0 = 0.f, ls1 = 0.f;
#pragma unroll
  for (int i = 0; i < 4; ++i) {
#pragma unroll
    for (int l = 0; l < 4; ++l) {
      const int c = cb + i * 4 + l;
      float e = 0.f;
      if (c <= r1) { e = __expf((v1[i][l] - m1) * SC); ls1 += e; }
      v1[i][l] = e;
    }
  }
  if (tid < 128) {
#pragma unroll
    for (int i = 0; i < 4; ++i) {
#pragma unroll
      for (int l = 0; l < 4; ++l) {
        const int c = cb + i * 4 + l;
        float e = 0.f;
        if (c <= r0) { e = __expf((v0[i][l] - m0) * SC); ls0 += e; }
        v0[i][l] = e;
      }
    }
  }
#pragma unroll
  for (int o = 32; o; o >>= 1) { ls0 += __shfl_xor(ls0, o); ls1 += __shfl_xor(ls1, o); }
  if ((tid & 63) == 0) { redA[tid >> 6] = ls0; redB[tid >> 6] = ls1; }
  __syncthreads();
  const float inv0 = 2.0f / (redA[0] + redA[1] + redA[2] + redA[3]);
  const float inv1 = 2.0f / (redB[0] + redB[1] + redB[2] + redB[3]);

#pragma unroll
  for (int i = 0; i < 4; ++i) {
    const int c = cb + i * 4;
    f32x4 o1v = {0.f, 0.f, 0.f, 0.f};
#pragma unroll
    for (int l = 0; l < 4; ++l) {
      const int cc = c + l;
      if (cc <= r1 && keep_bit((unsigned)(r1 * Tdim + cc))) o1v[l] = v1[i][l] * inv1;
    }
    *reinterpret_cast<f32x4*>(row1 + c) = o1v;
    f32x4 o0v = {0.f, 0.f, 0.f, 0.f};
    if (tid < 128) {
#pragma unroll
      for (int l = 0; l < 4; ++l) {
        const int cc = c + l;
        if (cc <= r0 && keep_bit((unsigned)(r0 * Tdim + cc))) o0v[l] = v0[i][l] * inv0;
      }
    }
    *reinterpret_cast<f32x4*>(row0 + c) = o0v;
  }
}

extern "C" void kernel_launch(void* const* d_in, const int* in_sizes, int n_in,
                              void* d_out, int out_size, void* d_ws, size_t ws_size,
                              hipStream_t stream) {
  const float* x  = (const float*)d_in[0];
  const float* Wq = (const float*)d_in[1];
  const float* Wk = (const float*)d_in[2];
  // d_in[3] (W_value) feeds only dead code in the reference — unused.
  float* S = (float*)d_out;
  char* ws = (char*)d_ws;
  bf16*  xb = (bf16*)(ws);                  //  8 MB: x bf16
  bf16*  qt = (bf16*)(ws + (8l  << 20));    //  2 MB: Wq^T bf16
  bf16*  kt = (bf16*)(ws + (10l << 20));    //  2 MB: Wk^T bf16
  float* Wp = (float*)(ws + (12l << 20));   // 16 MB: 4 split-K partials of G
  bf16*  G  = (bf16*)(ws + (28l << 20));    //  2 MB: G = Wk^T·Wq
  bf16*  P  = (bf16*)(ws + (30l << 20));    //  8 MB: P = x·(Wq^T·Wk)

  k_cast_bf16<<<(Tdim * Ddim / 4) / 256, 256, 0, stream>>>(x, xb, Tdim * Ddim / 4);
  k_tcast<<<dim3(32, 32, 2), 256, 0, stream>>>(Wq, Wk, qt, kt);

  // G partials: G[i,j] = sum_k Wk[k,i]*Wq[k,j], external split-K=4
  k_gemm<128, 1><<<dim3(32, 4), 512, 0, stream>>>(kt, qt, (void*)Wp, Ddim, Ddim,
                                                  Ddim, Ddim / 4, 1l << 20, 0);
  k_redcast<<<(Ddim * Ddim / 4) / 256, 256, 0, stream>>>(Wp, G);

  // P[m,n] = sum_k x[m,k]*G[n,k]
  k_gemm<128, 0><<<dim3(128, 1), 512, 0, stream>>>(xb, G, (void*)P, Ddim, Ddim,
                                                   Ddim, Ddim, 0, 0);
  // S[m,n] = sum_k P[m,k]*x[n,k], causal 256x256 blocks only
  k_gemm<256, 1><<<dim3(256, 1), 512, 0, stream>>>(P, xb, (void*)S, Tdim, Ddim,
                                                   Ddim, Ddim, 0, 1);

  k_softmax_drop<<<Tdim / 2, 256, 0, stream>>>(S);
}

// Round 8
// 188.603 us; speedup vs baseline: 2.4642x; 1.0338x over previous
//
#include <hip/hip_runtime.h>
#include <hip/hip_bf16.h>
#include <math.h>

// SelfAttention_v2: S = x·(Wq^T·Wk)·x^T, causal softmax (post-softmax mask +
// renorm == causal softmax), exact JAX partitionable-threefry dropout p=0.5.
// S-GEMM: m201-style 8-phase schedule, 256^2 tile, interleaved quadrant
// ownership, XOR-swizzled LDS, derived counted-vmcnt waits, triangular grid.

using bf16   = __bf16;
using bf16x8 = __attribute__((ext_vector_type(8))) __bf16;
using bf16x4 = __attribute__((ext_vector_type(4))) __bf16;
using f32x4  = __attribute__((ext_vector_type(4))) float;

constexpr int Tdim = 4096;
constexpr int Ddim = 1024;

// ---------------- cast f32 -> bf16, x4 vectorized ----------------
__global__ __launch_bounds__(256) void k_cast_bf16(const float* __restrict__ in,
                                                   bf16* __restrict__ out, int n4) {
  int i = blockIdx.x * 256 + threadIdx.x;
  if (i >= n4) return;
  f32x4 v = reinterpret_cast<const f32x4*>(in)[i];
  bf16x4 o;
  o[0] = (bf16)v[0]; o[1] = (bf16)v[1]; o[2] = (bf16)v[2]; o[3] = (bf16)v[3];
  reinterpret_cast<bf16x4*>(out)[i] = o;
}

// ---------------- fused transpose+cast for Wq,Wk ----------------
__global__ __launch_bounds__(256) void k_tcast(const float* __restrict__ q,
                                               const float* __restrict__ k,
                                               bf16* __restrict__ qt,
                                               bf16* __restrict__ kt) {
  const float* in = blockIdx.z ? k : q;
  bf16* out = blockIdx.z ? kt : qt;
  __shared__ float t[32][33];
  const int tx = threadIdx.x & 31;
  const int ty = threadIdx.x >> 5;
  const int r0 = blockIdx.y * 32;
  const int c0 = blockIdx.x * 32;
#pragma unroll
  for (int r = 0; r < 4; ++r)
    t[ty * 4 + r][tx] = in[(r0 + ty * 4 + r) * Ddim + c0 + tx];
  __syncthreads();
#pragma unroll
  for (int r = 0; r < 4; ++r)
    out[(c0 + ty * 4 + r) * Ddim + r0 + tx] = (bf16)t[tx][ty * 4 + r];
}

// ---------------- reduce 4 split-K partials + cast to bf16 ----------------
__global__ __launch_bounds__(256) void k_redcast(const float* __restrict__ p,
                                                 bf16* __restrict__ g) {
  const int i = blockIdx.x * 256 + threadIdx.x;
  f32x4 a = reinterpret_cast<const f32x4*>(p)[i];
  f32x4 b = reinterpret_cast<const f32x4*>(p + (1 << 20))[i];
  f32x4 c = reinterpret_cast<const f32x4*>(p + (2 << 20))[i];
  f32x4 d = reinterpret_cast<const f32x4*>(p + (3 << 20))[i];
  f32x4 s = a + b + c + d;
  bf16x4 o;
  o[0] = (bf16)s[0]; o[1] = (bf16)s[1]; o[2] = (bf16)s[2]; o[3] = (bf16)s[3];
  reinterpret_cast<bf16x4*>(g)[i] = o;
}

__device__ __forceinline__ void gll16(const bf16* g, bf16* l) {
  __builtin_amdgcn_global_load_lds(
      (const __attribute__((address_space(1))) void*)g,
      (__attribute__((address_space(3))) void*)l, 16, 0, 0);
}

// ---------------- generic GEMM (G and P), r7 quad-buffer version ----------
template<int BM, int OUTF32>
__global__ __launch_bounds__(512)
void k_gemm(const bf16* __restrict__ A, const bf16* __restrict__ B,
            void* __restrict__ Cv, int N, int lda, int ldb, int kLen,
            long cZs, int causal) {
  constexpr int FM  = BM / 32;
  __shared__ __align__(16) bf16 As[4][BM * 32];
  __shared__ __align__(16) bf16 Bs[4][256 * 32];

  int bx = blockIdx.x;
  {
    const int cpx = gridDim.x >> 3;
    bx = (bx & 7) * cpx + (bx >> 3);
  }
  const int nbn = N >> 8;
  const int bm = bx / nbn;
  const int bn = bx - bm * nbn;
  if (causal && bn > bm) return;

  const int tid  = threadIdx.x;
  const int lane = tid & 63;
  const int wid  = tid >> 6;
  const int wrr  = (wid >> 2) * (BM / 2);
  const int wcc  = (wid & 3) * 64;
  const int fr   = lane & 15;
  const int g8   = (lane >> 4) * 8;

  f32x4 acc[FM][4];
#pragma unroll
  for (int i = 0; i < FM; ++i)
#pragma unroll
    for (int j = 0; j < 4; ++j) acc[i][j] = (f32x4){0.f, 0.f, 0.f, 0.f};

  const bf16* Ag = A + (long)bm * BM * lda;
  const bf16* Bg = B + (long)bn * 256 * ldb;
  const int k0 = blockIdx.y * kLen;
  const int nt = kLen >> 5;

  const bf16* pa0 = Ag + (long)(tid >> 2) * lda + (tid & 3) * 8;
  const bf16* pa1 = pa0 + (long)128 * lda;
  const bf16* pb0 = Bg + (long)(tid >> 2) * ldb + (tid & 3) * 8;
  const bf16* pb1 = pb0 + (long)128 * ldb;

  auto stageA = [&](int buf, int kt) {
    gll16(pa0 + kt, &As[buf][tid * 8]);
    if constexpr (BM == 256) gll16(pa1 + kt, &As[buf][(tid + 512) * 8]);
  };
  auto stageB = [&](int buf, int kt) {
    gll16(pb0 + kt, &Bs[buf][tid * 8]);
    gll16(pb1 + kt, &Bs[buf][(tid + 512) * 8]);
  };

  stageA(0, k0);      stageB(0, k0);
  stageA(1, k0 + 32); stageB(1, k0 + 32);
  stageA(2, k0 + 64); stageB(2, k0 + 64);

  for (int t = 0; t < nt; ++t) {
    const int buf = t & 3;
    if (t < nt - 2) {
      if constexpr (BM == 256) asm volatile("s_waitcnt vmcnt(8)" ::: "memory");
      else                     asm volatile("s_waitcnt vmcnt(6)" ::: "memory");
    } else if (t == nt - 2) {
      if constexpr (BM == 256) asm volatile("s_waitcnt vmcnt(4)" ::: "memory");
      else                     asm volatile("s_waitcnt vmcnt(3)" ::: "memory");
    } else {
      asm volatile("s_waitcnt vmcnt(0)" ::: "memory");
    }
    __builtin_amdgcn_sched_barrier(0);
    __builtin_amdgcn_s_barrier();
    __builtin_amdgcn_sched_barrier(0);

    const int ks = k0 + (t + 3) * 32;
    const bool more = (t + 3) < nt;
    const int nbuf = (t + 3) & 3;

    bf16x8 av[4], bv[4];
#pragma unroll
    for (int n = 0; n < 4; ++n)
      bv[n] = *reinterpret_cast<const bf16x8*>(&Bs[buf][(wcc + n * 16 + fr) * 32 + g8]);
#pragma unroll
    for (int m = 0; m < 4; ++m)
      av[m] = *reinterpret_cast<const bf16x8*>(&As[buf][(wrr + m * 16 + fr) * 32 + g8]);
    if (more) stageA(nbuf, ks);
    __builtin_amdgcn_s_setprio(1);
#pragma unroll
    for (int m = 0; m < 4; ++m)
#pragma unroll
      for (int n = 0; n < 4; ++n)
        acc[m][n] = __builtin_amdgcn_mfma_f32_16x16x32_bf16(av[m], bv[n], acc[m][n], 0, 0, 0);
    __builtin_amdgcn_s_setprio(0);

    if constexpr (BM == 256) {
#pragma unroll
      for (int m = 0; m < 4; ++m)
        av[m] = *reinterpret_cast<const bf16x8*>(&As[buf][(wrr + (m + 4) * 16 + fr) * 32 + g8]);
      if (more) stageB(nbuf, ks);
      __builtin_amdgcn_s_setprio(1);
#pragma unroll
      for (int m = 0; m < 4; ++m)
#pragma unroll
        for (int n = 0; n < 4; ++n)
          acc[m + 4][n] = __builtin_amdgcn_mfma_f32_16x16x32_bf16(av[m], bv[n], acc[m + 4][n], 0, 0, 0);
      __builtin_amdgcn_s_setprio(0);
    } else {
      if (more) stageB(nbuf, ks);
    }
  }

  const int crow = (lane >> 4) * 4;
  const int ccol = lane & 15;
#pragma unroll
  for (int m = 0; m < FM; ++m)
#pragma unroll
    for (int n = 0; n < 4; ++n)
#pragma unroll
      for (int j = 0; j < 4; ++j) {
        const long row = (long)bm * BM + wrr + m * 16 + crow + j;
        const long col = (long)bn * 256 + wcc + n * 16 + ccol;
        const float v = acc[m][n][j];
        if (OUTF32) ((float*)Cv + (long)blockIdx.y * cZs)[row * N + col] = v;
        else        ((bf16*)Cv)[row * N + col] = (bf16)v;
      }
}

// ---------------- S-GEMM: 8-phase 256^2 causal (C = A·B^T, f32 out) --------
// Interleaved quadrant ownership: wave (wm,wn) owns rows {wm*64..+63} in both
// A-halves, cols {wn*32..+31} in both B-halves. Phase (qm,qn) consumes ONLY
// A-half qm + B-half qn. Stage order per tile t (for t+1): A0,B0,B1,A1.
// Waits (derived, induction-checked): vmcnt(4) at end of p0,p1,p3; none p2.
// Tail: vmcnt(2) p0, vmcnt(0) p1. LDS chunk-XOR swizzle (j ^ (row&7)).
__global__ __launch_bounds__(512, 2)
void k_gemm_s(const bf16* __restrict__ A, const bf16* __restrict__ B,
              float* __restrict__ C) {
  __shared__ __align__(16) bf16 As[2][2][128 * 64];
  __shared__ __align__(16) bf16 Bs[2][2][128 * 64];

  // triangular decode, XCD-chunked (136 = 8 * 17)
  int swz = (blockIdx.x & 7) * 17 + (blockIdx.x >> 3);
  int bm = (int)((sqrtf(8.f * swz + 1.f) - 1.f) * 0.5f);
  while ((bm + 1) * (bm + 2) / 2 <= swz) ++bm;
  while (bm * (bm + 1) / 2 > swz) --bm;
  const int bn = swz - bm * (bm + 1) / 2;

  const int tid  = threadIdx.x;
  const int lane = tid & 63;
  const int wid  = tid >> 6;
  const int wm   = wid >> 2, wn = wid & 3;
  const int fr   = lane & 15;
  const int lh   = lane >> 4;  // 0..3

  const bf16* Ag = A + (long)bm * 256 * Ddim;
  const bf16* Bg = B + (long)bn * 256 * Ddim;

  // staging: half-tile = 128 rows x 8 chunks(16B); thread covers chunks tid, tid+512
  const int r1 = tid >> 3,         c1 = ((tid & 7) ^ (r1 & 7)) * 8;
  const int r2 = (tid + 512) >> 3, c2 = ((tid & 7) ^ (r2 & 7)) * 8;
  const bf16* pA0a = Ag + (long)r1 * Ddim + c1;
  const bf16* pA0b = Ag + (long)r2 * Ddim + c2;
  const bf16* pA1a = pA0a + (long)128 * Ddim;
  const bf16* pA1b = pA0b + (long)128 * Ddim;
  const bf16* pB0a = Bg + (long)r1 * Ddim + c1;
  const bf16* pB0b = Bg + (long)r2 * Ddim + c2;
  const bf16* pB1a = pB0a + (long)128 * Ddim;
  const bf16* pB1b = pB0b + (long)128 * Ddim;
  const int d1 = tid * 8, d2 = (tid + 512) * 8;

  // which: 0=A-h0, 1=B-h0, 2=B-h1, 3=A-h1 (order matters for vmcnt schedule)
  auto stage = [&](int buf, int which, int kt) {
    switch (which) {
      case 0: gll16(pA0a + kt, &As[buf][0][d1]); gll16(pA0b + kt, &As[buf][0][d2]); break;
      case 1: gll16(pB0a + kt, &Bs[buf][0][d1]); gll16(pB0b + kt, &Bs[buf][0][d2]); break;
      case 2: gll16(pB1a + kt, &Bs[buf][1][d1]); gll16(pB1b + kt, &Bs[buf][1][d2]); break;
      case 3: gll16(pA1a + kt, &As[buf][1][d1]); gll16(pA1b + kt, &As[buf][1][d2]); break;
    }
  };
  auto rd = [&](const bf16* half, int row, int chunk) -> bf16x8 {
    return *reinterpret_cast<const bf16x8*>(half + row * 64 + ((chunk ^ (row & 7)) * 8));
  };

  f32x4 acc[8][4];
#pragma unroll
  for (int i = 0; i < 8; ++i)
#pragma unroll
    for (int j = 0; j < 4; ++j) acc[i][j] = (f32x4){0.f, 0.f, 0.f, 0.f};

  const int nt = Ddim / 64;  // 16 K-tiles
  stage(0, 0, 0); stage(0, 1, 0); stage(0, 2, 0); stage(0, 3, 0);
  asm volatile("s_waitcnt vmcnt(4)" ::: "memory");  // A0,B0 landed
  __builtin_amdgcn_sched_barrier(0);
  __builtin_amdgcn_s_barrier();

  bf16x8 av[8], bv0[4], bv1[4];
  for (int t = 0; t < nt; ++t) {
    const int buf = t & 1, nbuf = buf ^ 1;
    const int kt = (t + 1) * 64;
    const bool pf = (t + 1) < nt;
    const bf16* Ah0 = &As[buf][0][0];
    const bf16* Ah1 = &As[buf][1][0];
    const bf16* Bh0 = &Bs[buf][0][0];
    const bf16* Bh1 = &Bs[buf][1][0];

    // ---------- phase 0: (qm0, qn0) ----------
#pragma unroll
    for (int m = 0; m < 4; ++m) {
      const int row = wm * 64 + m * 16 + fr;
      av[m * 2]     = rd(Ah0, row, lh);
      av[m * 2 + 1] = rd(Ah0, row, 4 + lh);
    }
#pragma unroll
    for (int n = 0; n < 2; ++n) {
      const int row = wn * 32 + n * 16 + fr;
      bv0[n * 2]     = rd(Bh0, row, lh);
      bv0[n * 2 + 1] = rd(Bh0, row, 4 + lh);
    }
    if (pf) stage(nbuf, 0, kt);
    __builtin_amdgcn_s_barrier();
    asm volatile("s_waitcnt lgkmcnt(0)" ::: "memory");
    __builtin_amdgcn_sched_barrier(0);
    __builtin_amdgcn_s_setprio(1);
#pragma unroll
    for (int m = 0; m < 4; ++m)
#pragma unroll
      for (int n = 0; n < 2; ++n) {
        acc[m][n] = __builtin_amdgcn_mfma_f32_16x16x32_bf16(av[m*2],   bv0[n*2],   acc[m][n], 0, 0, 0);
        acc[m][n] = __builtin_amdgcn_mfma_f32_16x16x32_bf16(av[m*2+1], bv0[n*2+1], acc[m][n], 0, 0, 0);
      }
    __builtin_amdgcn_s_setprio(0);
    if (pf) asm volatile("s_waitcnt vmcnt(4)" ::: "memory");  // retire B1(t)
    else    asm volatile("s_waitcnt vmcnt(2)" ::: "memory");
    __builtin_amdgcn_sched_barrier(0);
    __builtin_amdgcn_s_barrier();

    // ---------- phase 1: (qm0, qn1) ----------
#pragma unroll
    for (int n = 0; n < 2; ++n) {
      const int row = wn * 32 + n * 16 + fr;
      bv1[n * 2]     = rd(Bh1, row, lh);
      bv1[n * 2 + 1] = rd(Bh1, row, 4 + lh);
    }
    if (pf) stage(nbuf, 1, kt);
    __builtin_amdgcn_s_barrier();
    asm volatile("s_waitcnt lgkmcnt(0)" ::: "memory");
    __builtin_amdgcn_sched_barrier(0);
    __builtin_amdgcn_s_setprio(1);
#pragma unroll
    for (int m = 0; m < 4; ++m)
#pragma unroll
      for (int n = 0; n < 2; ++n) {
        acc[m][2+n] = __builtin_amdgcn_mfma_f32_16x16x32_bf16(av[m*2],   bv1[n*2],   acc[m][2+n], 0, 0, 0);
        acc[m][2+n] = __builtin_amdgcn_mfma_f32_16x16x32_bf16(av[m*2+1], bv1[n*2+1], acc[m][2+n], 0, 0, 0);
      }
    __builtin_amdgcn_s_setprio(0);
    if (pf) asm volatile("s_waitcnt vmcnt(4)" ::: "memory");  // retire A1(t)
    else    asm volatile("s_waitcnt vmcnt(0)" ::: "memory");
    __builtin_amdgcn_sched_barrier(0);
    __builtin_amdgcn_s_barrier();

    // ---------- phase 2: (qm1, qn0) ----------
#pragma unroll
    for (int m = 0; m < 4; ++m) {
      const int row = wm * 64 + m * 16 + fr;
      av[m * 2]     = rd(Ah1, row, lh);
      av[m * 2 + 1] = rd(Ah1, row, 4 + lh);
    }
    if (pf) stage(nbuf, 2, kt);
    __builtin_amdgcn_s_barrier();
    asm volatile("s_waitcnt lgkmcnt(0)" ::: "memory");
    __builtin_amdgcn_sched_barrier(0);
    __builtin_amdgcn_s_setprio(1);
#pragma unroll
    for (int m = 0; m < 4; ++m)
#pragma unroll
      for (int n = 0; n < 2; ++n) {
        acc[4+m][n] = __builtin_amdgcn_mfma_f32_16x16x32_bf16(av[m*2],   bv0[n*2],   acc[4+m][n], 0, 0, 0);
        acc[4+m][n] = __builtin_amdgcn_mfma_f32_16x16x32_bf16(av[m*2+1], bv0[n*2+1], acc[4+m][n], 0, 0, 0);
      }
    __builtin_amdgcn_s_setprio(0);
    __builtin_amdgcn_s_barrier();

    // ---------- phase 3: (qm1, qn1) ----------
    if (pf) stage(nbuf, 3, kt);
    __builtin_amdgcn_s_barrier();
    __builtin_amdgcn_sched_barrier(0);
    __builtin_amdgcn_s_setprio(1);
#pragma unroll
    for (int m = 0; m < 4; ++m)
#pragma unroll
      for (int n = 0; n < 2; ++n) {
        acc[4+m][2+n] = __builtin_amdgcn_mfma_f32_16x16x32_bf16(av[m*2],   bv1[n*2],   acc[4+m][2+n], 0, 0, 0);
        acc[4+m][2+n] = __builtin_amdgcn_mfma_f32_16x16x32_bf16(av[m*2+1], bv1[n*2+1], acc[4+m][2+n], 0, 0, 0);
      }
    __builtin_amdgcn_s_setprio(0);
    if (pf) {
      asm volatile("s_waitcnt vmcnt(4)" ::: "memory");  // retire A0',B0' for next p0
      __builtin_amdgcn_sched_barrier(0);
    }
    __builtin_amdgcn_s_barrier();
  }

  // epilogue
  const int crow = (lane >> 4) * 4;
  const int ccol = lane & 15;
#pragma unroll
  for (int qm = 0; qm < 2; ++qm)
#pragma unroll
    for (int m = 0; m < 4; ++m)
#pragma unroll
      for (int qn = 0; qn < 2; ++qn)
#pragma unroll
        for (int n = 0; n < 2; ++n)
#pragma unroll
          for (int j = 0; j < 4; ++j) {
            const long row = (long)bm * 256 + qm * 128 + wm * 64 + m * 16 + crow + j;
            const long col = (long)bn * 256 + qn * 128 + wn * 32 + n * 16 + ccol;
            C[row * Tdim + col] = acc[qm * 4 + m][qn * 2 + n][j];
          }
}

// ---------------- JAX threefry2x32, key = (0,123) ----------------
__device__ __forceinline__ unsigned rotl32(unsigned v, int d) {
  return (v << d) | (v >> (32 - d));
}
__device__ __forceinline__ void threefry_123(unsigned x0, unsigned x1,
                                             unsigned& o0, unsigned& o1) {
  const unsigned ks0 = 0u, ks1 = 123u;
  const unsigned ks2 = 0x1BD11BDAu ^ ks0 ^ ks1;
  x0 += ks0; x1 += ks1;
#define TF_R4(a, b, c, d)                                   \
  x0 += x1; x1 = rotl32(x1, a); x1 ^= x0;                   \
  x0 += x1; x1 = rotl32(x1, b); x1 ^= x0;                   \
  x0 += x1; x1 = rotl32(x1, c); x1 ^= x0;                   \
  x0 += x1; x1 = rotl32(x1, d); x1 ^= x0;
  TF_R4(13, 15, 26, 6);  x0 += ks1; x1 += ks2 + 1u;
  TF_R4(17, 29, 16, 24); x0 += ks2; x1 += ks0 + 2u;
  TF_R4(13, 15, 26, 6);  x0 += ks0; x1 += ks1 + 3u;
  TF_R4(17, 29, 16, 24); x0 += ks1; x1 += ks2 + 4u;
  TF_R4(13, 15, 26, 6);  x0 += ks2; x1 += ks0 + 5u;
#undef TF_R4
  o0 = x0; o1 = x1;
}
__device__ __forceinline__ bool keep_bit(unsigned i) {
  unsigned o0, o1;
  threefry_123(0u, i, o0, o1);
  return ((o0 ^ o1) & 0x80000000u) == 0u;
}

// ---------------- fused in-place causal softmax + dropout ----------------
// Balanced pairing: block b handles rows r0=b and r1=4095-b (total ~4097 cols).
__global__ __launch_bounds__(256) void k_softmax_drop(float* __restrict__ S) {
  const int b  = blockIdx.x;
  const int r0 = b, r1 = Tdim - 1 - b;
  const int tid = threadIdx.x;
  const int cb  = tid * 16;
  __shared__ float redA[4], redB[4];

  float* row0 = S + (long)r0 * Tdim;
  float* row1 = S + (long)r1 * Tdim;

  f32x4 v1[4], v0[4];
  float lm0 = -3.0e38f, lm1 = -3.0e38f;
#pragma unroll
  for (int i = 0; i < 4; ++i) {
    const int c = cb + i * 4;
    f32x4 v = (c <= r1) ? *reinterpret_cast<const f32x4*>(row1 + c)
                        : (f32x4){0.f, 0.f, 0.f, 0.f};
#pragma unroll
    for (int l = 0; l < 4; ++l) {
      if (c + l > r1) v[l] = -3.0e38f;
      lm1 = fmaxf(lm1, v[l]);
    }
    v1[i] = v;
  }
#pragma unroll
  for (int i = 0; i < 4; ++i) {
    const int c = cb + i * 4;
    f32x4 v = (c <= r0) ? *reinterpret_cast<const f32x4*>(row0 + c)
                        : (f32x4){0.f, 0.f, 0.f, 0.f};
#pragma unroll
    for (int l = 0; l < 4; ++l) {
      if (c + l > r0) v[l] = -3.0e38f;
      lm0 = fmaxf(lm0, v[l]);
    }
    v0[i] = v;
  }
#pragma unroll
  for (int o = 32; o; o >>= 1) {
    lm0 = fmaxf(lm0, __shfl_xor(lm0, o));
    lm1 = fmaxf(lm1, __shfl_xor(lm1, o));
  }
  if ((tid & 63) == 0) { redA[tid >> 6] = lm0; redB[tid >> 6] = lm1; }
  __syncthreads();
  const float m0 = fmaxf(fmaxf(redA[0], redA[1]), fmaxf(redA[2], redA[3]));
  const float m1 = fmaxf(fmaxf(redB[0], redB[1]), fmaxf(redB[2], redB[3]));
  __syncthreads();

  constexpr float SC = 1.0f / 32.0f;  // 1/sqrt(1024)
  float ls0 = 0.f, ls1 = 0.f;
#pragma unroll
  for (int i = 0; i < 4; ++i) {
#pragma unroll
    for (int l = 0; l < 4; ++l) {
      const int c = cb + i * 4 + l;
      float e = 0.f;
      if (c <= r1) { e = __expf((v1[i][l] - m1) * SC); ls1 += e; }
      v1[i][l] = e;
      float e0 = 0.f;
      if (c <= r0) { e0 = __expf((v0[i][l] - m0) * SC); ls0 += e0; }
      v0[i][l] = e0;
    }
  }
#pragma unroll
  for (int o = 32; o; o >>= 1) { ls0 += __shfl_xor(ls0, o); ls1 += __shfl_xor(ls1, o); }
  if ((tid & 63) == 0) { redA[tid >> 6] = ls0; redB[tid >> 6] = ls1; }
  __syncthreads();
  const float inv0 = 2.0f / (redA[0] + redA[1] + redA[2] + redA[3]);
  const float inv1 = 2.0f / (redB[0] + redB[1] + redB[2] + redB[3]);

#pragma unroll
  for (int i = 0; i < 4; ++i) {
    const int c = cb + i * 4;
    f32x4 o1v = {0.f, 0.f, 0.f, 0.f};
#pragma unroll
    for (int l = 0; l < 4; ++l) {
      const int cc = c + l;
      if (cc <= r1 && keep_bit((unsigned)(r1 * Tdim + cc))) o1v[l] = v1[i][l] * inv1;
    }
    *reinterpret_cast<f32x4*>(row1 + c) = o1v;
    f32x4 o0v = {0.f, 0.f, 0.f, 0.f};
#pragma unroll
    for (int l = 0; l < 4; ++l) {
      const int cc = c + l;
      if (cc <= r0 && keep_bit((unsigned)(r0 * Tdim + cc))) o0v[l] = v0[i][l] * inv0;
    }
    *reinterpret_cast<f32x4*>(row0 + c) = o0v;
  }
}

extern "C" void kernel_launch(void* const* d_in, const int* in_sizes, int n_in,
                              void* d_out, int out_size, void* d_ws, size_t ws_size,
                              hipStream_t stream) {
  const float* x  = (const float*)d_in[0];
  const float* Wq = (const float*)d_in[1];
  const float* Wk = (const float*)d_in[2];
  // d_in[3] (W_value) feeds only dead code in the reference — unused.
  float* S = (float*)d_out;
  char* ws = (char*)d_ws;
  bf16*  xb = (bf16*)(ws);                  //  8 MB: x bf16
  bf16*  qt = (bf16*)(ws + (8l  << 20));    //  2 MB: Wq^T bf16
  bf16*  kt = (bf16*)(ws + (10l << 20));    //  2 MB: Wk^T bf16
  float* Wp = (float*)(ws + (12l << 20));   // 16 MB: 4 split-K partials of G
  bf16*  G  = (bf16*)(ws + (28l << 20));    //  2 MB: G = Wk^T·Wq
  bf16*  P  = (bf16*)(ws + (30l << 20));    //  8 MB: P = x·(Wq^T·Wk)

  k_cast_bf16<<<(Tdim * Ddim / 4) / 256, 256, 0, stream>>>(x, xb, Tdim * Ddim / 4);
  k_tcast<<<dim3(32, 32, 2), 256, 0, stream>>>(Wq, Wk, qt, kt);

  // G partials: G[i,j] = sum_k Wk[k,i]*Wq[k,j], external split-K=4
  k_gemm<128, 1><<<dim3(32, 4), 512, 0, stream>>>(kt, qt, (void*)Wp, Ddim, Ddim,
                                                  Ddim, Ddim / 4, 1l << 20, 0);
  k_redcast<<<(Ddim * Ddim / 4) / 256, 256, 0, stream>>>(Wp, G);

  // P[m,n] = sum_k x[m,k]*G[n,k]
  k_gemm<128, 0><<<dim3(128, 1), 512, 0, stream>>>(xb, G, (void*)P, Ddim, Ddim,
                                                   Ddim, Ddim, 0, 0);
  // S[m,n] = sum_k P[m,k]*x[n,k], 8-phase causal triangular grid
  k_gemm_s<<<136, 512, 0, stream>>>(P, xb, S);

  k_softmax_drop<<<Tdim / 2, 256, 0, stream>>>(S);
}